// Round 5
// baseline (317.272 us; speedup 1.0000x reference)
//
#include <hip/hip_runtime.h>
#include <hip/hip_bf16.h>

#define D_ 128
#define N_ 8192
#define K_ 256

typedef __attribute__((ext_vector_type(8))) short sh8;   // 8 bf16 = 4 VGPRs
typedef __attribute__((ext_vector_type(4))) float f4;    // 4 fp32

__device__ __forceinline__ unsigned short f2bf(float f) {
  union { float f; unsigned u; } x; x.f = f;
  unsigned r = x.u + 0x7fffu + ((x.u >> 16) & 1u);       // RNE
  return (unsigned short)(r >> 16);
}

__device__ __forceinline__ float bf2f(unsigned short h) {
  union { unsigned u; float f; } x; x.u = ((unsigned)h) << 16;
  return x.f;
}

// ---------------------------------------------------------------------------
// prep_x: X (fp32 [D][N]) -> Xbt (bf16 [N][D]) transpose, copy X -> out rows 0..D-1
// grid (N/64, D/64), block 256
__global__ void prep_x_k(const float* __restrict__ X, float* __restrict__ out,
                         unsigned short* __restrict__ Xbt) {
  __shared__ float tile[64][65];
  const int n0 = blockIdx.x * 64;
  const int e0 = blockIdx.y * 64;
  const int t = threadIdx.x;
  const int col = t & 63;
  const int r4 = t >> 6;
  for (int rr = 0; rr < 64; rr += 4) {
    int e = rr + r4;
    float v = X[(size_t)(e0 + e) * N_ + n0 + col];
    tile[e][col] = v;
    out[(size_t)(e0 + e) * N_ + n0 + col] = v;   // exact fp32 copy of X
  }
  __syncthreads();
  const int chunk = t & 15;
  for (int iter = 0; iter < 4; ++iter) {
    int nl = iter * 16 + (t >> 4);
    ushort4 w;
    w.x = f2bf(tile[chunk * 4 + 0][nl]);
    w.y = f2bf(tile[chunk * 4 + 1][nl]);
    w.z = f2bf(tile[chunk * 4 + 2][nl]);
    w.w = f2bf(tile[chunk * 4 + 3][nl]);
    *(ushort4*)&Xbt[(size_t)(n0 + nl) * D_ + e0 + chunk * 4] = w;
  }
}

// ---------------------------------------------------------------------------
// prep_a: N_A (fp32 [D][D][K], layout d,e,c) -> Ab (bf16 [K][D][D], layout c,d,e)
// grid (K/64, D/64, D), block 256
__global__ void prep_a_k(const float* __restrict__ NA, unsigned short* __restrict__ Ab) {
  __shared__ float tile[64][65];   // [e][c]
  const int c0 = blockIdx.x * 64;
  const int e0 = blockIdx.y * 64;
  const int d  = blockIdx.z;
  const int t = threadIdx.x;
  const int cc = t & 63;
  const int r4 = t >> 6;
  const size_t dbase = (size_t)d * D_ * K_;
  for (int rr = 0; rr < 64; rr += 4) {
    int e = rr + r4;
    tile[e][cc] = NA[dbase + (size_t)(e0 + e) * K_ + c0 + cc];
  }
  __syncthreads();
  const int chunk = t & 15;
  for (int iter = 0; iter < 4; ++iter) {
    int cl = iter * 16 + (t >> 4);
    ushort4 w;
    w.x = f2bf(tile[chunk * 4 + 0][cl]);
    w.y = f2bf(tile[chunk * 4 + 1][cl]);
    w.z = f2bf(tile[chunk * 4 + 2][cl]);
    w.w = f2bf(tile[chunk * 4 + 3][cl]);
    *(ushort4*)&Ab[(size_t)(c0 + cl) * D_ * D_ + (size_t)d * D_ + e0 + chunk * 4] = w;
  }
}

// ---------------------------------------------------------------------------
// amu v3: Amut[c][d] = sum_e Ab[c][d][e] * N_mu[e][c] (bf16 A, fp32 accumulate).
// grid (K), block 256. Coalesced plane load into LDS, then per-thread half-row dot.
__global__ __launch_bounds__(256) void amu_k(const unsigned short* __restrict__ Ab,
                                             const float* __restrict__ Nmu,
                                             float* __restrict__ Amut) {
  __shared__ unsigned short pl[D_ * D_];   // 32 KB
  __shared__ float mu[D_];
  const int c = blockIdx.x;
  const int t = threadIdx.x;
  const sh8* src = (const sh8*)(Ab + (size_t)c * D_ * D_);
  sh8* dst = (sh8*)pl;
#pragma unroll
  for (int it = 0; it < 8; ++it)
    dst[it * 256 + t] = src[it * 256 + t];
  if (t < D_) mu[t] = Nmu[(size_t)t * K_ + c];
  __syncthreads();
  const int d = t >> 1;
  const int half = t & 1;
  const unsigned short* row = &pl[d * D_ + half * 64];
  const float* mh = &mu[half * 64];
  float s0 = 0.f, s1 = 0.f;
#pragma unroll
  for (int e = 0; e < 32; ++e) {
    s0 += bf2f(row[e]) * mh[e];
    s1 += bf2f(row[e + 32]) * mh[e + 32];
  }
  float s = s0 + s1;
  s += __shfl_xor(s, 1, 64);
  if (half == 0) Amut[(size_t)c * D_ + d] = s;
}

// ---------------------------------------------------------------------------
// main: sq[c][n] = sum_d (sum_e A[d,e,c] X[e,n] - Amu[d,c])^2
// grid (N/256, K/8), block 256 (4 waves). Wave w: j in [w*64,+64), all 128 d.
// Double-buffered HALF-plane staging (16 KB each): phase p = (ci = p>>1, h = p&1);
// one barrier per phase; stage(p+1) issued right AFTER the barrier so the whole
// MFMA block of phase p hides the staging latency (the round-4 version waited on
// the stage immediately — 57% idle). LDS 33 KB -> 4 blocks/CU.
__global__ __launch_bounds__(256, 4) void main_k(
    const unsigned short* __restrict__ Ab, const unsigned short* __restrict__ Xbt,
    const float* __restrict__ Amut, float* __restrict__ sqws) {
  __shared__ unsigned short Asw[2][8192];   // 2 x 16 KB, frag-ordered half-planes
  __shared__ float amus[2][D_];             // 1 KB, double-buffered per-c row
  const int t = threadIdx.x;
  const int w = t >> 6;
  const int L = t & 63;
  const int m = L & 15;
  const int q = L >> 4;
  const int n0 = blockIdx.x * 256;
  const int c0 = blockIdx.y * 8;

  // persistent X B-fragments: wave w covers j = n0 + w*64 + jt*16 + m, k = ks*32+q*8
  sh8 xf[4][4];
  {
    const unsigned short* xb = Xbt + (size_t)(n0 + w * 64 + m) * D_ + q * 8;
#pragma unroll
    for (int jt = 0; jt < 4; ++jt)
#pragma unroll
      for (int ks = 0; ks < 4; ++ks)
        xf[jt][ks] = *(const sh8*)&xb[(size_t)jt * 16 * D_ + ks * 32];
  }

  // staging offsets: thread stages 4 slots sl = w + 4*it (wave-uniform dest base),
  // lane scatter L*16. Half-plane h source byte = h*16384 + soff[it].
  int soff[4];
#pragma unroll
  for (int it = 0; it < 4; ++it) {
    int sl = w + it * 4;              // 0..15
    int dtl = sl >> 2, ks = sl & 3;
    soff[it] = (dtl * 16 + m) * 256 + ks * 64 + q * 16;
  }
  const char* plane0 = (const char*)(Ab + (size_t)c0 * D_ * D_);

  // pre-stage phase 0 (ci=0, h=0) + amus[0]
#pragma unroll
  for (int it = 0; it < 4; ++it)
    __builtin_amdgcn_global_load_lds((const unsigned int*)(plane0 + soff[it]),
        (unsigned int*)((char*)&Asw[0][0] + (w + it * 4) * 1024), 16, 0, 0);
  if (t < 32)
    __builtin_amdgcn_global_load_lds((const unsigned int*)(Amut + (size_t)c0 * D_ + t * 4),
        (unsigned int*)&amus[0][0], 16, 0, 0);

  const f4 zero = {0.f, 0.f, 0.f, 0.f};
  float ss0 = 0.f, ss1 = 0.f, ss2 = 0.f, ss3 = 0.f;

  for (int p = 0; p < 16; ++p) {
    const int ci = p >> 1;
    const int h = p & 1;
    const int buf = p & 1;
    __syncthreads();   // drains stage(p) — issued one full compute phase ago

    // issue stage(p+1) NOW, before compute(p): hidden under the MFMA block
    if (p < 15) {
      const int pn = p + 1;
      const char* src = plane0 + (size_t)(pn >> 1) * 32768 + (size_t)(pn & 1) * 16384;
#pragma unroll
      for (int it = 0; it < 4; ++it)
        __builtin_amdgcn_global_load_lds((const unsigned int*)(src + soff[it]),
            (unsigned int*)((char*)&Asw[pn & 1][0] + (w + it * 4) * 1024), 16, 0, 0);
      if (h == 1 && t < 32)
        __builtin_amdgcn_global_load_lds(
            (const unsigned int*)(Amut + (size_t)(c0 + ci + 1) * D_ + t * 4),
            (unsigned int*)&amus[(ci + 1) & 1][0], 16, 0, 0);
    }

    if (h == 0) { ss0 = 0.f; ss1 = 0.f; ss2 = 0.f; ss3 = 0.f; }
    const char* abase = (const char*)&Asw[buf][0] + L * 16;
    const float* amub = &amus[ci & 1][h * 64];
#pragma unroll
    for (int dtl = 0; dtl < 4; ++dtl) {
      sh8 afr[4];
#pragma unroll
      for (int ks = 0; ks < 4; ++ks)
        afr[ks] = *(const sh8*)(abase + (dtl * 4 + ks) * 1024);
      f4 amu = *(const f4*)&amub[dtl * 16 + q * 4];
#pragma unroll
      for (int jt = 0; jt < 4; ++jt) {
        f4 acc = __builtin_amdgcn_mfma_f32_16x16x32_bf16(afr[0], xf[jt][0], zero, 0, 0, 0);
        acc = __builtin_amdgcn_mfma_f32_16x16x32_bf16(afr[1], xf[jt][1], acc, 0, 0, 0);
        acc = __builtin_amdgcn_mfma_f32_16x16x32_bf16(afr[2], xf[jt][2], acc, 0, 0, 0);
        acc = __builtin_amdgcn_mfma_f32_16x16x32_bf16(afr[3], xf[jt][3], acc, 0, 0, 0);
        float v0 = acc[0] - amu[0];
        float v1 = acc[1] - amu[1];
        float v2 = acc[2] - amu[2];
        float v3 = acc[3] - amu[3];
        float sj = v0 * v0 + v1 * v1 + v2 * v2 + v3 * v3;
        if (jt == 0) ss0 += sj; else if (jt == 1) ss1 += sj;
        else if (jt == 2) ss2 += sj; else ss3 += sj;
      }
    }

    if (h == 1) {
      // full 128-d sums: each lane holds its quad's 4 rows x 8 dt-tiles; xor-16/32
      // folds the 4 quads. Then quad q owns col-tile jt=q: j = w*64 + L.
      ss0 += __shfl_xor(ss0, 16, 64);  ss0 += __shfl_xor(ss0, 32, 64);
      ss1 += __shfl_xor(ss1, 16, 64);  ss1 += __shfl_xor(ss1, 32, 64);
      ss2 += __shfl_xor(ss2, 16, 64);  ss2 += __shfl_xor(ss2, 32, 64);
      ss3 += __shfl_xor(ss3, 16, 64);  ss3 += __shfl_xor(ss3, 32, 64);
      float sel = (q == 0) ? ss0 : (q == 1) ? ss1 : (q == 2) ? ss2 : ss3;
      sqws[(size_t)(c0 + ci) * N_ + n0 + w * 64 + L] = sel;
    }
  }
}

// ---------------------------------------------------------------------------
// softmax over c per n; writes Pi to out rows D_..D_+K_-1
// grid (N/16 = 512), block 256: nl = t&15 (16 n), cg = t>>4 (16 groups x 16 c).
// exp values held in registers between passes; LDS padded +1 (2-way conflicts free).
__global__ __launch_bounds__(256) void softmax_k(const float* __restrict__ sqws,
                                                 const float* __restrict__ gptr,
                                                 float* __restrict__ out) {
  __shared__ float s_ld[K_][17];   // ~17 KB
  __shared__ float red[16][16];
  __shared__ float red2[16][16];
  const int t = threadIdx.x;
  const int n0 = blockIdx.x * 16;
  const float gamma = *gptr;
  const int nl = t & 15;
  const int cg = t >> 4;
  for (int it = 0; it < 16; ++it) {
    int c = it * 16 + cg;
    s_ld[c][nl] = sqws[(size_t)c * N_ + n0 + nl];
  }
  __syncthreads();
  float mxp = -1e30f;
#pragma unroll
  for (int cc = 0; cc < 16; ++cc)
    mxp = fmaxf(mxp, gamma * s_ld[cg * 16 + cc][nl]);
  red[cg][nl] = mxp;
  __syncthreads();
  float mx = red[0][nl];
#pragma unroll
  for (int g2 = 1; g2 < 16; ++g2) mx = fmaxf(mx, red[g2][nl]);
  float ex[16];
  float z = 0.f;
#pragma unroll
  for (int cc = 0; cc < 16; ++cc) {
    ex[cc] = __expf(gamma * s_ld[cg * 16 + cc][nl] - mx);
    z += ex[cc];
  }
  red2[cg][nl] = z;
  __syncthreads();
  float zz = red2[0][nl];
#pragma unroll
  for (int g2 = 1; g2 < 16; ++g2) zz += red2[g2][nl];
  float rz = 1.f / zz;
#pragma unroll
  for (int cc = 0; cc < 16; ++cc)
    out[(size_t)(D_ + cg * 16 + cc) * N_ + n0 + nl] = ex[cc] * rz;
}

// ---------------------------------------------------------------------------
extern "C" void kernel_launch(void* const* d_in, const int* in_sizes, int n_in,
                              void* d_out, int out_size, void* d_ws, size_t ws_size,
                              hipStream_t stream) {
  const float* X   = (const float*)d_in[0];
  const float* NA  = (const float*)d_in[1];
  const float* Nmu = (const float*)d_in[2];
  const float* g   = (const float*)d_in[3];
  float* out = (float*)d_out;
  char* ws = (char*)d_ws;

  unsigned short* Xbt = (unsigned short*)(ws);                 // 2 MB
  unsigned short* Ab  = (unsigned short*)(ws + 2097152);       // 8.39 MB
  float* Amut         = (float*)(ws + 10485760);               // 128 KB
  float* sqws         = (float*)(ws + 10616832);               // 8.39 MB

  hipLaunchKernelGGL(prep_x_k, dim3(N_ / 64, D_ / 64), dim3(256), 0, stream, X, out, Xbt);
  hipLaunchKernelGGL(prep_a_k, dim3(K_ / 64, D_ / 64, D_), dim3(256), 0, stream, NA, Ab);
  hipLaunchKernelGGL(amu_k, dim3(K_), dim3(256), 0, stream, Ab, Nmu, Amut);
  hipLaunchKernelGGL(main_k, dim3(N_ / 256, K_ / 8), dim3(256), 0, stream, Ab, Xbt, Amut, sqws);
  hipLaunchKernelGGL(softmax_k, dim3(N_ / 16), dim3(256), 0, stream, sqws, g, out);
}

// Round 6
// 275.581 us; speedup vs baseline: 1.1513x; 1.1513x over previous
//
#include <hip/hip_runtime.h>
#include <hip/hip_bf16.h>

#define D_ 128
#define N_ 8192
#define K_ 256

typedef __attribute__((ext_vector_type(8))) short sh8;   // 8 bf16 = 4 VGPRs
typedef __attribute__((ext_vector_type(4))) float f4;    // 4 fp32

__device__ __forceinline__ unsigned short f2bf(float f) {
  union { float f; unsigned u; } x; x.f = f;
  unsigned r = x.u + 0x7fffu + ((x.u >> 16) & 1u);       // RNE
  return (unsigned short)(r >> 16);
}

__device__ __forceinline__ float bf2f(unsigned short h) {
  union { unsigned u; float f; } x; x.u = ((unsigned)h) << 16;
  return x.f;
}

// ---------------------------------------------------------------------------
// prep_x: X (fp32 [D][N]) -> Xbt (bf16 [N][D]) transpose, copy X -> out rows 0..D-1
// grid (N/64, D/64), block 256
__global__ void prep_x_k(const float* __restrict__ X, float* __restrict__ out,
                         unsigned short* __restrict__ Xbt) {
  __shared__ float tile[64][65];
  const int n0 = blockIdx.x * 64;
  const int e0 = blockIdx.y * 64;
  const int t = threadIdx.x;
  const int col = t & 63;
  const int r4 = t >> 6;
  for (int rr = 0; rr < 64; rr += 4) {
    int e = rr + r4;
    float v = X[(size_t)(e0 + e) * N_ + n0 + col];
    tile[e][col] = v;
    out[(size_t)(e0 + e) * N_ + n0 + col] = v;   // exact fp32 copy of X
  }
  __syncthreads();
  const int chunk = t & 15;
  for (int iter = 0; iter < 4; ++iter) {
    int nl = iter * 16 + (t >> 4);
    ushort4 w;
    w.x = f2bf(tile[chunk * 4 + 0][nl]);
    w.y = f2bf(tile[chunk * 4 + 1][nl]);
    w.z = f2bf(tile[chunk * 4 + 2][nl]);
    w.w = f2bf(tile[chunk * 4 + 3][nl]);
    *(ushort4*)&Xbt[(size_t)(n0 + nl) * D_ + e0 + chunk * 4] = w;
  }
}

// ---------------------------------------------------------------------------
// prep_a: N_A (fp32 [D][D][K], layout d,e,c) -> Ab (bf16 [K][D][D], layout c,d,e)
// grid (K/64, D/64, D), block 256
__global__ void prep_a_k(const float* __restrict__ NA, unsigned short* __restrict__ Ab) {
  __shared__ float tile[64][65];   // [e][c]
  const int c0 = blockIdx.x * 64;
  const int e0 = blockIdx.y * 64;
  const int d  = blockIdx.z;
  const int t = threadIdx.x;
  const int cc = t & 63;
  const int r4 = t >> 6;
  const size_t dbase = (size_t)d * D_ * K_;
  for (int rr = 0; rr < 64; rr += 4) {
    int e = rr + r4;
    tile[e][cc] = NA[dbase + (size_t)(e0 + e) * K_ + c0 + cc];
  }
  __syncthreads();
  const int chunk = t & 15;
  for (int iter = 0; iter < 4; ++iter) {
    int cl = iter * 16 + (t >> 4);
    ushort4 w;
    w.x = f2bf(tile[chunk * 4 + 0][cl]);
    w.y = f2bf(tile[chunk * 4 + 1][cl]);
    w.z = f2bf(tile[chunk * 4 + 2][cl]);
    w.w = f2bf(tile[chunk * 4 + 3][cl]);
    *(ushort4*)&Ab[(size_t)(c0 + cl) * D_ * D_ + (size_t)d * D_ + e0 + chunk * 4] = w;
  }
}

// ---------------------------------------------------------------------------
// amu v3: Amut[c][d] = sum_e Ab[c][d][e] * N_mu[e][c] (bf16 A, fp32 accumulate).
// grid (K), block 256. Coalesced plane load into LDS, then per-thread half-row dot.
__global__ __launch_bounds__(256) void amu_k(const unsigned short* __restrict__ Ab,
                                             const float* __restrict__ Nmu,
                                             float* __restrict__ Amut) {
  __shared__ unsigned short pl[D_ * D_];   // 32 KB
  __shared__ float mu[D_];
  const int c = blockIdx.x;
  const int t = threadIdx.x;
  const sh8* src = (const sh8*)(Ab + (size_t)c * D_ * D_);
  sh8* dst = (sh8*)pl;
#pragma unroll
  for (int it = 0; it < 8; ++it)
    dst[it * 256 + t] = src[it * 256 + t];
  if (t < D_) mu[t] = Nmu[(size_t)t * K_ + c];
  __syncthreads();
  const int d = t >> 1;
  const int half = t & 1;
  const unsigned short* row = &pl[d * D_ + half * 64];
  const float* mh = &mu[half * 64];
  float s0 = 0.f, s1 = 0.f;
#pragma unroll
  for (int e = 0; e < 32; ++e) {
    s0 += bf2f(row[e]) * mh[e];
    s1 += bf2f(row[e + 32]) * mh[e + 32];
  }
  float s = s0 + s1;
  s += __shfl_xor(s, 1, 64);
  if (half == 0) Amut[(size_t)c * D_ + d] = s;
}

// ---------------------------------------------------------------------------
// main: sq[c][n] = sum_d (sum_e A[d,e,c] X[e,n] - Amu[d,c])^2
// grid (N/256, K/8), block 256 (4 waves). Wave w: j in [w*64,+64), all 128 d.
// Double-buffered half-plane staging with STATIC buffers (Asw0 = d 0..63,
// Asw1 = d 64..127): per ci — [barrier; stage h1; compute h0] then
// [barrier; stage next h0; compute h1 + epilogue]. Each stage has one full
// MFMA block (~1200 cyc wall at 4 waves/SIMD) before its drain barrier.
// Register budget at waves=4 is 128 unified; keep xf in AGPR (r4 fit: 124/128).
__global__ __launch_bounds__(256, 4) void main_k(
    const unsigned short* __restrict__ Ab, const unsigned short* __restrict__ Xbt,
    const float* __restrict__ Amut, float* __restrict__ sqws) {
  __shared__ unsigned short Asw0[8192];   // 16 KB: h=0 half-plane, frag-ordered
  __shared__ unsigned short Asw1[8192];   // 16 KB: h=1 half-plane
  __shared__ float amus[2][D_];           // 1 KB, double-buffered per-c row
  const int t = threadIdx.x;
  const int w = t >> 6;
  const int L = t & 63;
  const int m = L & 15;
  const int q = L >> 4;
  const int n0 = blockIdx.x * 256;
  const int c0 = blockIdx.y * 8;

  // persistent X B-fragments: wave w covers j = n0 + w*64 + jt*16 + m, k = ks*32+q*8
  sh8 xf[4][4];
  {
    const unsigned short* xb = Xbt + (size_t)(n0 + w * 64 + m) * D_ + q * 8;
#pragma unroll
    for (int jt = 0; jt < 4; ++jt)
#pragma unroll
      for (int ks = 0; ks < 4; ++ks)
        xf[jt][ks] = *(const sh8*)&xb[(size_t)jt * 16 * D_ + ks * 32];
  }

  // staging: thread stages 4 slots sl = w + 4*it (wave-uniform dest base + lane*16).
  // slot sl = dtl*4+ks; source byte (within half-plane) = (dtl*16+m)*256 + ks*64 + q*16.
  int soff[4];
#pragma unroll
  for (int it = 0; it < 4; ++it) {
    int sl = w + it * 4;
    int dtl = sl >> 2, ks = sl & 3;
    soff[it] = (dtl * 16 + m) * 256 + ks * 64 + q * 16;
  }
  const char* plane0 = (const char*)(Ab + (size_t)c0 * D_ * D_);

  // pre-stage (ci=0, h=0) + amus[0]
#pragma unroll
  for (int it = 0; it < 4; ++it)
    __builtin_amdgcn_global_load_lds((const unsigned int*)(plane0 + soff[it]),
        (unsigned int*)((char*)Asw0 + (w + it * 4) * 1024), 16, 0, 0);
  if (t < 32)
    __builtin_amdgcn_global_load_lds((const unsigned int*)(Amut + (size_t)c0 * D_ + t * 4),
        (unsigned int*)&amus[0][0], 16, 0, 0);

  const f4 zero = {0.f, 0.f, 0.f, 0.f};
  const char* abase0 = (const char*)Asw0 + L * 16;
  const char* abase1 = (const char*)Asw1 + L * 16;

  for (int ci = 0; ci < 8; ++ci) {
    const char* plane = plane0 + (size_t)ci * 32768;
    const float* amub = &amus[ci & 1][0];
    float ss0 = 0.f, ss1 = 0.f, ss2 = 0.f, ss3 = 0.f;

    __syncthreads();   // drains stage of (ci, h=0) — issued a full phase ago
    // stage (ci, h=1) now; hidden under the h=0 MFMA block
#pragma unroll
    for (int it = 0; it < 4; ++it)
      __builtin_amdgcn_global_load_lds((const unsigned int*)(plane + 16384 + soff[it]),
          (unsigned int*)((char*)Asw1 + (w + it * 4) * 1024), 16, 0, 0);

    // compute h=0 (d 0..63)
#pragma unroll
    for (int dtl = 0; dtl < 4; ++dtl) {
      sh8 afr[4];
#pragma unroll
      for (int ks = 0; ks < 4; ++ks)
        afr[ks] = *(const sh8*)(abase0 + (dtl * 4 + ks) * 1024);
      f4 amu = *(const f4*)&amub[dtl * 16 + q * 4];
#pragma unroll
      for (int jt = 0; jt < 4; ++jt) {
        f4 acc = __builtin_amdgcn_mfma_f32_16x16x32_bf16(afr[0], xf[jt][0], zero, 0, 0, 0);
        acc = __builtin_amdgcn_mfma_f32_16x16x32_bf16(afr[1], xf[jt][1], acc, 0, 0, 0);
        acc = __builtin_amdgcn_mfma_f32_16x16x32_bf16(afr[2], xf[jt][2], acc, 0, 0, 0);
        acc = __builtin_amdgcn_mfma_f32_16x16x32_bf16(afr[3], xf[jt][3], acc, 0, 0, 0);
        float v0 = acc[0] - amu[0];
        float v1 = acc[1] - amu[1];
        float v2 = acc[2] - amu[2];
        float v3 = acc[3] - amu[3];
        float sj = v0 * v0 + v1 * v1 + v2 * v2 + v3 * v3;
        if (jt == 0) ss0 += sj; else if (jt == 1) ss1 += sj;
        else if (jt == 2) ss2 += sj; else ss3 += sj;
      }
    }

    __syncthreads();   // drains stage of (ci, h=1)
    // stage (ci+1, h=0) + amus[(ci+1)&1] now; hidden under the h=1 MFMA block
    if (ci < 7) {
#pragma unroll
      for (int it = 0; it < 4; ++it)
        __builtin_amdgcn_global_load_lds((const unsigned int*)(plane + 32768 + soff[it]),
            (unsigned int*)((char*)Asw0 + (w + it * 4) * 1024), 16, 0, 0);
      if (t < 32)
        __builtin_amdgcn_global_load_lds(
            (const unsigned int*)(Amut + (size_t)(c0 + ci + 1) * D_ + t * 4),
            (unsigned int*)&amus[(ci + 1) & 1][0], 16, 0, 0);
    }

    // compute h=1 (d 64..127)
#pragma unroll
    for (int dtl = 0; dtl < 4; ++dtl) {
      sh8 afr[4];
#pragma unroll
      for (int ks = 0; ks < 4; ++ks)
        afr[ks] = *(const sh8*)(abase1 + (dtl * 4 + ks) * 1024);
      f4 amu = *(const f4*)&amub[64 + dtl * 16 + q * 4];
#pragma unroll
      for (int jt = 0; jt < 4; ++jt) {
        f4 acc = __builtin_amdgcn_mfma_f32_16x16x32_bf16(afr[0], xf[jt][0], zero, 0, 0, 0);
        acc = __builtin_amdgcn_mfma_f32_16x16x32_bf16(afr[1], xf[jt][1], acc, 0, 0, 0);
        acc = __builtin_amdgcn_mfma_f32_16x16x32_bf16(afr[2], xf[jt][2], acc, 0, 0, 0);
        acc = __builtin_amdgcn_mfma_f32_16x16x32_bf16(afr[3], xf[jt][3], acc, 0, 0, 0);
        float v0 = acc[0] - amu[0];
        float v1 = acc[1] - amu[1];
        float v2 = acc[2] - amu[2];
        float v3 = acc[3] - amu[3];
        float sj = v0 * v0 + v1 * v1 + v2 * v2 + v3 * v3;
        if (jt == 0) ss0 += sj; else if (jt == 1) ss1 += sj;
        else if (jt == 2) ss2 += sj; else ss3 += sj;
      }
    }

    // epilogue: fold quads -> full 128-d sums (replicated over q); quad q owns
    // col-tile jt=q: j = w*64 + q*16 + m = w*64 + L (coalesced 256B/wave store)
    ss0 += __shfl_xor(ss0, 16, 64);  ss0 += __shfl_xor(ss0, 32, 64);
    ss1 += __shfl_xor(ss1, 16, 64);  ss1 += __shfl_xor(ss1, 32, 64);
    ss2 += __shfl_xor(ss2, 16, 64);  ss2 += __shfl_xor(ss2, 32, 64);
    ss3 += __shfl_xor(ss3, 16, 64);  ss3 += __shfl_xor(ss3, 32, 64);
    float sel = (q == 0) ? ss0 : (q == 1) ? ss1 : (q == 2) ? ss2 : ss3;
    sqws[(size_t)(c0 + ci) * N_ + n0 + w * 64 + L] = sel;
  }
}

// ---------------------------------------------------------------------------
// softmax over c per n; writes Pi to out rows D_..D_+K_-1
// grid (N/16 = 512), block 256: nl = t&15 (16 n), cg = t>>4 (16 groups x 16 c).
__global__ __launch_bounds__(256) void softmax_k(const float* __restrict__ sqws,
                                                 const float* __restrict__ gptr,
                                                 float* __restrict__ out) {
  __shared__ float s_ld[K_][17];   // ~17 KB
  __shared__ float red[16][16];
  __shared__ float red2[16][16];
  const int t = threadIdx.x;
  const int n0 = blockIdx.x * 16;
  const float gamma = *gptr;
  const int nl = t & 15;
  const int cg = t >> 4;
  for (int it = 0; it < 16; ++it) {
    int c = it * 16 + cg;
    s_ld[c][nl] = sqws[(size_t)c * N_ + n0 + nl];
  }
  __syncthreads();
  float mxp = -1e30f;
#pragma unroll
  for (int cc = 0; cc < 16; ++cc)
    mxp = fmaxf(mxp, gamma * s_ld[cg * 16 + cc][nl]);
  red[cg][nl] = mxp;
  __syncthreads();
  float mx = red[0][nl];
#pragma unroll
  for (int g2 = 1; g2 < 16; ++g2) mx = fmaxf(mx, red[g2][nl]);
  float ex[16];
  float z = 0.f;
#pragma unroll
  for (int cc = 0; cc < 16; ++cc) {
    ex[cc] = __expf(gamma * s_ld[cg * 16 + cc][nl] - mx);
    z += ex[cc];
  }
  red2[cg][nl] = z;
  __syncthreads();
  float zz = red2[0][nl];
#pragma unroll
  for (int g2 = 1; g2 < 16; ++g2) zz += red2[g2][nl];
  float rz = 1.f / zz;
#pragma unroll
  for (int cc = 0; cc < 16; ++cc)
    out[(size_t)(D_ + cg * 16 + cc) * N_ + n0 + nl] = ex[cc] * rz;
}

// ---------------------------------------------------------------------------
extern "C" void kernel_launch(void* const* d_in, const int* in_sizes, int n_in,
                              void* d_out, int out_size, void* d_ws, size_t ws_size,
                              hipStream_t stream) {
  const float* X   = (const float*)d_in[0];
  const float* NA  = (const float*)d_in[1];
  const float* Nmu = (const float*)d_in[2];
  const float* g   = (const float*)d_in[3];
  float* out = (float*)d_out;
  char* ws = (char*)d_ws;

  unsigned short* Xbt = (unsigned short*)(ws);                 // 2 MB
  unsigned short* Ab  = (unsigned short*)(ws + 2097152);       // 8.39 MB
  float* Amut         = (float*)(ws + 10485760);               // 128 KB
  float* sqws         = (float*)(ws + 10616832);               // 8.39 MB

  hipLaunchKernelGGL(prep_x_k, dim3(N_ / 64, D_ / 64), dim3(256), 0, stream, X, out, Xbt);
  hipLaunchKernelGGL(prep_a_k, dim3(K_ / 64, D_ / 64, D_), dim3(256), 0, stream, NA, Ab);
  hipLaunchKernelGGL(amu_k, dim3(K_), dim3(256), 0, stream, Ab, Nmu, Amut);
  hipLaunchKernelGGL(main_k, dim3(N_ / 256, K_ / 8), dim3(256), 0, stream, Ab, Xbt, Amut, sqws);
  hipLaunchKernelGGL(softmax_k, dim3(N_ / 16), dim3(256), 0, stream, sqws, g, out);
}

// Round 7
// 154.966 us; speedup vs baseline: 2.0474x; 1.7783x over previous
//
#include <hip/hip_runtime.h>
#include <hip/hip_bf16.h>

#define D_ 128
#define N_ 8192
#define K_ 256

typedef __attribute__((ext_vector_type(8))) short sh8;   // 8 bf16 = 4 VGPRs
typedef __attribute__((ext_vector_type(4))) float f4;    // 4 fp32

__device__ __forceinline__ unsigned short f2bf(float f) {
  union { float f; unsigned u; } x; x.f = f;
  unsigned r = x.u + 0x7fffu + ((x.u >> 16) & 1u);       // RNE
  return (unsigned short)(r >> 16);
}

__device__ __forceinline__ float bf2f(unsigned short h) {
  union { unsigned u; float f; } x; x.u = ((unsigned)h) << 16;
  return x.f;
}

// ---------------------------------------------------------------------------
// prep_x: X (fp32 [D][N]) -> Xbt (bf16 [N][D]) transpose, copy X -> out rows 0..D-1
// grid (N/64, D/64), block 256
__global__ void prep_x_k(const float* __restrict__ X, float* __restrict__ out,
                         unsigned short* __restrict__ Xbt) {
  __shared__ float tile[64][65];
  const int n0 = blockIdx.x * 64;
  const int e0 = blockIdx.y * 64;
  const int t = threadIdx.x;
  const int col = t & 63;
  const int r4 = t >> 6;
  for (int rr = 0; rr < 64; rr += 4) {
    int e = rr + r4;
    float v = X[(size_t)(e0 + e) * N_ + n0 + col];
    tile[e][col] = v;
    out[(size_t)(e0 + e) * N_ + n0 + col] = v;   // exact fp32 copy of X
  }
  __syncthreads();
  const int chunk = t & 15;
  for (int iter = 0; iter < 4; ++iter) {
    int nl = iter * 16 + (t >> 4);
    ushort4 w;
    w.x = f2bf(tile[chunk * 4 + 0][nl]);
    w.y = f2bf(tile[chunk * 4 + 1][nl]);
    w.z = f2bf(tile[chunk * 4 + 2][nl]);
    w.w = f2bf(tile[chunk * 4 + 3][nl]);
    *(ushort4*)&Xbt[(size_t)(n0 + nl) * D_ + e0 + chunk * 4] = w;
  }
}

// ---------------------------------------------------------------------------
// prep_a: N_A (fp32 [D][D][K], layout d,e,c) -> Ab (bf16 [K][D][D], layout c,d,e)
// grid (K/64, D/64, D), block 256
__global__ void prep_a_k(const float* __restrict__ NA, unsigned short* __restrict__ Ab) {
  __shared__ float tile[64][65];   // [e][c]
  const int c0 = blockIdx.x * 64;
  const int e0 = blockIdx.y * 64;
  const int d  = blockIdx.z;
  const int t = threadIdx.x;
  const int cc = t & 63;
  const int r4 = t >> 6;
  const size_t dbase = (size_t)d * D_ * K_;
  for (int rr = 0; rr < 64; rr += 4) {
    int e = rr + r4;
    tile[e][cc] = NA[dbase + (size_t)(e0 + e) * K_ + c0 + cc];
  }
  __syncthreads();
  const int chunk = t & 15;
  for (int iter = 0; iter < 4; ++iter) {
    int cl = iter * 16 + (t >> 4);
    ushort4 w;
    w.x = f2bf(tile[chunk * 4 + 0][cl]);
    w.y = f2bf(tile[chunk * 4 + 1][cl]);
    w.z = f2bf(tile[chunk * 4 + 2][cl]);
    w.w = f2bf(tile[chunk * 4 + 3][cl]);
    *(ushort4*)&Ab[(size_t)(c0 + cl) * D_ * D_ + (size_t)d * D_ + e0 + chunk * 4] = w;
  }
}

// ---------------------------------------------------------------------------
// amu v3: Amut[c][d] = sum_e Ab[c][d][e] * N_mu[e][c] (bf16 A, fp32 accumulate).
// grid (K), block 256. Coalesced plane load into LDS, then per-thread half-row dot.
__global__ __launch_bounds__(256) void amu_k(const unsigned short* __restrict__ Ab,
                                             const float* __restrict__ Nmu,
                                             float* __restrict__ Amut) {
  __shared__ unsigned short pl[D_ * D_];   // 32 KB
  __shared__ float mu[D_];
  const int c = blockIdx.x;
  const int t = threadIdx.x;
  const sh8* src = (const sh8*)(Ab + (size_t)c * D_ * D_);
  sh8* dst = (sh8*)pl;
#pragma unroll
  for (int it = 0; it < 8; ++it)
    dst[it * 256 + t] = src[it * 256 + t];
  if (t < D_) mu[t] = Nmu[(size_t)t * K_ + c];
  __syncthreads();
  const int d = t >> 1;
  const int half = t & 1;
  const unsigned short* row = &pl[d * D_ + half * 64];
  const float* mh = &mu[half * 64];
  float s0 = 0.f, s1 = 0.f;
#pragma unroll
  for (int e = 0; e < 32; ++e) {
    s0 += bf2f(row[e]) * mh[e];
    s1 += bf2f(row[e + 32]) * mh[e + 32];
  }
  float s = s0 + s1;
  s += __shfl_xor(s, 1, 64);
  if (half == 0) Amut[(size_t)c * D_ + d] = s;
}

// ---------------------------------------------------------------------------
// main: sq[c][n] = sum_d (sum_e A[d,e,c] X[e,n] - Amu[d,c])^2
// grid (N/256, K/8), block 256 (4 waves). Wave w: j in [w*64,+64), all 128 d.
// Double-buffered half-plane staging with STATIC buffers (Asw0 = d 0..63,
// Asw1 = d 64..127): per ci — [barrier; stage h1; compute h0] then
// [barrier; stage next h0; compute h1 + epilogue].
// launch_bounds(256,3): 170-reg budget. waves=4 (rounds 5/6) made the allocator
// spill xf to scratch -> 700 MB HBM spill traffic, MfmaUtil 14%. 3 waves/SIMD
// with the structural pipeline is the stable point.
__global__ __launch_bounds__(256, 3) void main_k(
    const unsigned short* __restrict__ Ab, const unsigned short* __restrict__ Xbt,
    const float* __restrict__ Amut, float* __restrict__ sqws) {
  __shared__ unsigned short Asw0[8192];   // 16 KB: h=0 half-plane, frag-ordered
  __shared__ unsigned short Asw1[8192];   // 16 KB: h=1 half-plane
  __shared__ float amus[2][D_];           // 1 KB, double-buffered per-c row
  const int t = threadIdx.x;
  const int w = t >> 6;
  const int L = t & 63;
  const int m = L & 15;
  const int q = L >> 4;
  const int n0 = blockIdx.x * 256;
  const int c0 = blockIdx.y * 8;

  // persistent X B-fragments: wave w covers j = n0 + w*64 + jt*16 + m, k = ks*32+q*8
  sh8 xf[4][4];
  {
    const unsigned short* xb = Xbt + (size_t)(n0 + w * 64 + m) * D_ + q * 8;
#pragma unroll
    for (int jt = 0; jt < 4; ++jt)
#pragma unroll
      for (int ks = 0; ks < 4; ++ks)
        xf[jt][ks] = *(const sh8*)&xb[(size_t)jt * 16 * D_ + ks * 32];
  }

  // staging: thread stages 4 slots sl = w + 4*it (wave-uniform dest base + lane*16).
  // slot sl = dtl*4+ks; source byte (within half-plane) = (dtl*16+m)*256 + ks*64 + q*16.
  int soff[4];
#pragma unroll
  for (int it = 0; it < 4; ++it) {
    int sl = w + it * 4;
    int dtl = sl >> 2, ks = sl & 3;
    soff[it] = (dtl * 16 + m) * 256 + ks * 64 + q * 16;
  }
  const char* plane0 = (const char*)(Ab + (size_t)c0 * D_ * D_);

  // pre-stage (ci=0, h=0) + amus[0]
#pragma unroll
  for (int it = 0; it < 4; ++it)
    __builtin_amdgcn_global_load_lds((const unsigned int*)(plane0 + soff[it]),
        (unsigned int*)((char*)Asw0 + (w + it * 4) * 1024), 16, 0, 0);
  if (t < 32)
    __builtin_amdgcn_global_load_lds((const unsigned int*)(Amut + (size_t)c0 * D_ + t * 4),
        (unsigned int*)&amus[0][0], 16, 0, 0);

  const f4 zero = {0.f, 0.f, 0.f, 0.f};
  const char* abase0 = (const char*)Asw0 + L * 16;
  const char* abase1 = (const char*)Asw1 + L * 16;

  for (int ci = 0; ci < 8; ++ci) {
    const char* plane = plane0 + (size_t)ci * 32768;
    const float* amub = &amus[ci & 1][0];
    float ss0 = 0.f, ss1 = 0.f, ss2 = 0.f, ss3 = 0.f;

    __syncthreads();   // drains stage of (ci, h=0) — issued a full phase ago
    // stage (ci, h=1) now; hidden under the h=0 MFMA block
#pragma unroll
    for (int it = 0; it < 4; ++it)
      __builtin_amdgcn_global_load_lds((const unsigned int*)(plane + 16384 + soff[it]),
          (unsigned int*)((char*)Asw1 + (w + it * 4) * 1024), 16, 0, 0);

    // compute h=0 (d 0..63)
#pragma unroll
    for (int dtl = 0; dtl < 4; ++dtl) {
      sh8 afr[4];
#pragma unroll
      for (int ks = 0; ks < 4; ++ks)
        afr[ks] = *(const sh8*)(abase0 + (dtl * 4 + ks) * 1024);
      f4 amu = *(const f4*)&amub[dtl * 16 + q * 4];
#pragma unroll
      for (int jt = 0; jt < 4; ++jt) {
        f4 acc = __builtin_amdgcn_mfma_f32_16x16x32_bf16(afr[0], xf[jt][0], zero, 0, 0, 0);
        acc = __builtin_amdgcn_mfma_f32_16x16x32_bf16(afr[1], xf[jt][1], acc, 0, 0, 0);
        acc = __builtin_amdgcn_mfma_f32_16x16x32_bf16(afr[2], xf[jt][2], acc, 0, 0, 0);
        acc = __builtin_amdgcn_mfma_f32_16x16x32_bf16(afr[3], xf[jt][3], acc, 0, 0, 0);
        float v0 = acc[0] - amu[0];
        float v1 = acc[1] - amu[1];
        float v2 = acc[2] - amu[2];
        float v3 = acc[3] - amu[3];
        float sj = v0 * v0 + v1 * v1 + v2 * v2 + v3 * v3;
        if (jt == 0) ss0 += sj; else if (jt == 1) ss1 += sj;
        else if (jt == 2) ss2 += sj; else ss3 += sj;
      }
    }

    __syncthreads();   // drains stage of (ci, h=1)
    // stage (ci+1, h=0) + amus[(ci+1)&1] now; hidden under the h=1 MFMA block
    if (ci < 7) {
#pragma unroll
      for (int it = 0; it < 4; ++it)
        __builtin_amdgcn_global_load_lds((const unsigned int*)(plane + 32768 + soff[it]),
            (unsigned int*)((char*)Asw0 + (w + it * 4) * 1024), 16, 0, 0);
      if (t < 32)
        __builtin_amdgcn_global_load_lds(
            (const unsigned int*)(Amut + (size_t)(c0 + ci + 1) * D_ + t * 4),
            (unsigned int*)&amus[(ci + 1) & 1][0], 16, 0, 0);
    }

    // compute h=1 (d 64..127)
#pragma unroll
    for (int dtl = 0; dtl < 4; ++dtl) {
      sh8 afr[4];
#pragma unroll
      for (int ks = 0; ks < 4; ++ks)
        afr[ks] = *(const sh8*)(abase1 + (dtl * 4 + ks) * 1024);
      f4 amu = *(const f4*)&amub[64 + dtl * 16 + q * 4];
#pragma unroll
      for (int jt = 0; jt < 4; ++jt) {
        f4 acc = __builtin_amdgcn_mfma_f32_16x16x32_bf16(afr[0], xf[jt][0], zero, 0, 0, 0);
        acc = __builtin_amdgcn_mfma_f32_16x16x32_bf16(afr[1], xf[jt][1], acc, 0, 0, 0);
        acc = __builtin_amdgcn_mfma_f32_16x16x32_bf16(afr[2], xf[jt][2], acc, 0, 0, 0);
        acc = __builtin_amdgcn_mfma_f32_16x16x32_bf16(afr[3], xf[jt][3], acc, 0, 0, 0);
        float v0 = acc[0] - amu[0];
        float v1 = acc[1] - amu[1];
        float v2 = acc[2] - amu[2];
        float v3 = acc[3] - amu[3];
        float sj = v0 * v0 + v1 * v1 + v2 * v2 + v3 * v3;
        if (jt == 0) ss0 += sj; else if (jt == 1) ss1 += sj;
        else if (jt == 2) ss2 += sj; else ss3 += sj;
      }
    }

    // epilogue: fold quads -> full 128-d sums (replicated over q); quad q owns
    // col-tile jt=q: j = w*64 + q*16 + m = w*64 + L (coalesced 256B/wave store)
    ss0 += __shfl_xor(ss0, 16, 64);  ss0 += __shfl_xor(ss0, 32, 64);
    ss1 += __shfl_xor(ss1, 16, 64);  ss1 += __shfl_xor(ss1, 32, 64);
    ss2 += __shfl_xor(ss2, 16, 64);  ss2 += __shfl_xor(ss2, 32, 64);
    ss3 += __shfl_xor(ss3, 16, 64);  ss3 += __shfl_xor(ss3, 32, 64);
    float sel = (q == 0) ? ss0 : (q == 1) ? ss1 : (q == 2) ? ss2 : ss3;
    sqws[(size_t)(c0 + ci) * N_ + n0 + w * 64 + L] = sel;
  }
}

// ---------------------------------------------------------------------------
// softmax over c per n; writes Pi to out rows D_..D_+K_-1
// grid (N/16 = 512), block 256: nl = t&15 (16 n), cg = t>>4 (16 groups x 16 c).
__global__ __launch_bounds__(256) void softmax_k(const float* __restrict__ sqws,
                                                 const float* __restrict__ gptr,
                                                 float* __restrict__ out) {
  __shared__ float s_ld[K_][17];   // ~17 KB
  __shared__ float red[16][16];
  __shared__ float red2[16][16];
  const int t = threadIdx.x;
  const int n0 = blockIdx.x * 16;
  const float gamma = *gptr;
  const int nl = t & 15;
  const int cg = t >> 4;
  for (int it = 0; it < 16; ++it) {
    int c = it * 16 + cg;
    s_ld[c][nl] = sqws[(size_t)c * N_ + n0 + nl];
  }
  __syncthreads();
  float mxp = -1e30f;
#pragma unroll
  for (int cc = 0; cc < 16; ++cc)
    mxp = fmaxf(mxp, gamma * s_ld[cg * 16 + cc][nl]);
  red[cg][nl] = mxp;
  __syncthreads();
  float mx = red[0][nl];
#pragma unroll
  for (int g2 = 1; g2 < 16; ++g2) mx = fmaxf(mx, red[g2][nl]);
  float ex[16];
  float z = 0.f;
#pragma unroll
  for (int cc = 0; cc < 16; ++cc) {
    ex[cc] = __expf(gamma * s_ld[cg * 16 + cc][nl] - mx);
    z += ex[cc];
  }
  red2[cg][nl] = z;
  __syncthreads();
  float zz = red2[0][nl];
#pragma unroll
  for (int g2 = 1; g2 < 16; ++g2) zz += red2[g2][nl];
  float rz = 1.f / zz;
#pragma unroll
  for (int cc = 0; cc < 16; ++cc)
    out[(size_t)(D_ + cg * 16 + cc) * N_ + n0 + nl] = ex[cc] * rz;
}

// ---------------------------------------------------------------------------
extern "C" void kernel_launch(void* const* d_in, const int* in_sizes, int n_in,
                              void* d_out, int out_size, void* d_ws, size_t ws_size,
                              hipStream_t stream) {
  const float* X   = (const float*)d_in[0];
  const float* NA  = (const float*)d_in[1];
  const float* Nmu = (const float*)d_in[2];
  const float* g   = (const float*)d_in[3];
  float* out = (float*)d_out;
  char* ws = (char*)d_ws;

  unsigned short* Xbt = (unsigned short*)(ws);                 // 2 MB
  unsigned short* Ab  = (unsigned short*)(ws + 2097152);       // 8.39 MB
  float* Amut         = (float*)(ws + 10485760);               // 128 KB
  float* sqws         = (float*)(ws + 10616832);               // 8.39 MB

  hipLaunchKernelGGL(prep_x_k, dim3(N_ / 64, D_ / 64), dim3(256), 0, stream, X, out, Xbt);
  hipLaunchKernelGGL(prep_a_k, dim3(K_ / 64, D_ / 64, D_), dim3(256), 0, stream, NA, Ab);
  hipLaunchKernelGGL(amu_k, dim3(K_), dim3(256), 0, stream, Ab, Nmu, Amut);
  hipLaunchKernelGGL(main_k, dim3(N_ / 256, K_ / 8), dim3(256), 0, stream, Ab, Xbt, Amut, sqws);
  hipLaunchKernelGGL(softmax_k, dim3(N_ / 16), dim3(256), 0, stream, sqws, g, out);
}

// Round 8
// 144.104 us; speedup vs baseline: 2.2017x; 1.0754x over previous
//
#include <hip/hip_runtime.h>

#define D_ 128
#define N_ 8192
#define K_ 256

typedef __attribute__((ext_vector_type(4))) float f4;    // 4 fp32

// ---------------------------------------------------------------------------
// prep_x: X (fp32 [D][N]) -> Xf8 (fp8 e4m3 [N][D]) transpose, copy X -> out rows 0..D-1
// grid (N/64, D/64), block 256
__global__ void prep_x_k(const float* __restrict__ X, float* __restrict__ out,
                         unsigned char* __restrict__ Xf8) {
  __shared__ float tile[64][65];
  const int n0 = blockIdx.x * 64;
  const int e0 = blockIdx.y * 64;
  const int t = threadIdx.x;
  const int col = t & 63;
  const int r4 = t >> 6;
  for (int rr = 0; rr < 64; rr += 4) {
    int e = rr + r4;
    float v = X[(size_t)(e0 + e) * N_ + n0 + col];
    tile[e][col] = v;
    out[(size_t)(e0 + e) * N_ + n0 + col] = v;   // exact fp32 copy of X
  }
  __syncthreads();
  const int chunk = t & 15;
  for (int iter = 0; iter < 4; ++iter) {
    int nl = iter * 16 + (t >> 4);
    float v0 = tile[chunk * 4 + 0][nl];
    float v1 = tile[chunk * 4 + 1][nl];
    float v2 = tile[chunk * 4 + 2][nl];
    float v3 = tile[chunk * 4 + 3][nl];
    int pk = __builtin_amdgcn_cvt_pk_fp8_f32(v0, v1, 0, false);
    pk = __builtin_amdgcn_cvt_pk_fp8_f32(v2, v3, pk, true);
    *(int*)&Xf8[(size_t)(n0 + nl) * D_ + e0 + chunk * 4] = pk;
  }
}

// ---------------------------------------------------------------------------
// prep_a: N_A (fp32 [D][D][K]) -> Af8s: fp8, FRAGMENT-ORDERED per c-plane (16 KB):
//   plane offset(dtl,kp,L=q*16+m, b16) = dtl*2048 + kp*1024 + L*16 + b16
//   b16 in [0,8):  A[d=dtl*16+m][e = kp*64 +      q*8 + b16]   (ks=2kp)
//   b16 in [8,16): A[d=dtl*16+m][e = kp*64 + 32 + q*8 + b16-8] (ks=2kp+1)
// So main_k staging is a pure linear copy and LDS reads are conflict-free L*16.
// grid (8 dtl, 16 c-groups), block 256.
__global__ __launch_bounds__(256) void prep_a_k(const float* __restrict__ NA,
                                                unsigned char* __restrict__ Af8s) {
  __shared__ unsigned char AT[16 * 2184];   // [cl][d*136 + e], strides avoid conflicts
  const int dtl = blockIdx.x;
  const int c0 = blockIdx.y * 16;
  const int t = threadIdx.x;
  const int cl = t & 15;
  const int pe = t >> 4;
  // load + convert: 2048 (d,e) pairs, 16 per iter
#pragma unroll 4
  for (int iter = 0; iter < 128; ++iter) {
    int p = iter * 16 + pe;
    int d = p >> 7, e = p & 127;
    float v = NA[((size_t)(dtl * 16 + d) * D_ + e) * K_ + c0 + cl];
    int pk = __builtin_amdgcn_cvt_pk_fp8_f32(v, v, 0, false);
    AT[cl * 2184 + d * 136 + e] = (unsigned char)(pk & 0xff);
  }
  __syncthreads();
  // write phase: 32 units (cl,kp), each one wave x 16 B per lane
  const int w = t >> 6, L = t & 63, q = L >> 4, m = L & 15;
  for (int it = 0; it < 8; ++it) {
    int u = w + it * 4;
    int ucl = u >> 1, kp = u & 1;
    const unsigned char* base = AT + ucl * 2184 + m * 136 + kp * 64 + q * 8;
    unsigned long long lo = *(const unsigned long long*)(base);        // ks=2kp
    unsigned long long hi = *(const unsigned long long*)(base + 32);   // ks=2kp+1
    ulonglong2 val; val.x = lo; val.y = hi;
    *(ulonglong2*)(Af8s + (size_t)(c0 + ucl) * 16384 + dtl * 2048 + kp * 1024 + L * 16) = val;
  }
}

// ---------------------------------------------------------------------------
// amu: Amut[c][d] = sum_e fp8(A)[d,e,c] * N_mu[e,c]  (same fp8 A as the MFMA).
// grid (K), block (D). Reads the frag-ordered layout.
__global__ __launch_bounds__(128) void amu_k(const unsigned char* __restrict__ Af8s,
                                             const float* __restrict__ Nmu,
                                             float* __restrict__ Amut) {
  __shared__ float mu[D_];
  const int c = blockIdx.x;
  const int t = threadIdx.x;   // = d
  mu[t] = Nmu[(size_t)t * K_ + c];
  __syncthreads();
  const int dtl = t >> 4, m = t & 15;
  const unsigned char* base = Af8s + (size_t)c * 16384 + dtl * 2048;
  float s = 0.f;
#pragma unroll
  for (int kp = 0; kp < 2; ++kp)
#pragma unroll
    for (int q = 0; q < 4; ++q) {
      const unsigned char* p = base + kp * 1024 + (q * 16 + m) * 16;
      int2 v0 = *(const int2*)(p);
      int2 v1 = *(const int2*)(p + 8);
      int e0 = kp * 64 + q * 8;
      s += __builtin_amdgcn_cvt_f32_fp8(v0.x, 0) * mu[e0 + 0];
      s += __builtin_amdgcn_cvt_f32_fp8(v0.x, 1) * mu[e0 + 1];
      s += __builtin_amdgcn_cvt_f32_fp8(v0.x, 2) * mu[e0 + 2];
      s += __builtin_amdgcn_cvt_f32_fp8(v0.x, 3) * mu[e0 + 3];
      s += __builtin_amdgcn_cvt_f32_fp8(v0.y, 0) * mu[e0 + 4];
      s += __builtin_amdgcn_cvt_f32_fp8(v0.y, 1) * mu[e0 + 5];
      s += __builtin_amdgcn_cvt_f32_fp8(v0.y, 2) * mu[e0 + 6];
      s += __builtin_amdgcn_cvt_f32_fp8(v0.y, 3) * mu[e0 + 7];
      s += __builtin_amdgcn_cvt_f32_fp8(v1.x, 0) * mu[e0 + 32];
      s += __builtin_amdgcn_cvt_f32_fp8(v1.x, 1) * mu[e0 + 33];
      s += __builtin_amdgcn_cvt_f32_fp8(v1.x, 2) * mu[e0 + 34];
      s += __builtin_amdgcn_cvt_f32_fp8(v1.x, 3) * mu[e0 + 35];
      s += __builtin_amdgcn_cvt_f32_fp8(v1.y, 0) * mu[e0 + 36];
      s += __builtin_amdgcn_cvt_f32_fp8(v1.y, 1) * mu[e0 + 37];
      s += __builtin_amdgcn_cvt_f32_fp8(v1.y, 2) * mu[e0 + 38];
      s += __builtin_amdgcn_cvt_f32_fp8(v1.y, 3) * mu[e0 + 39];
    }
  Amut[(size_t)c * D_ + t] = s;
}

// ---------------------------------------------------------------------------
// main (fp8): sq[c][n] = sum_d (sum_e A X - Amu)^2
// grid (N/256, K/8), block 256 (4 waves). Wave w: j in [w*64,+64), ALL 128 d.
// fp8 halves xf (32 regs), A-frags (8 B), and LDS traffic vs bf16 -> fits
// launch_bounds(256,4) without spill (the bf16 version could not).
// Full-plane (16 KB) double buffer, static A0s/A1s, stage issued right after
// each barrier so a full 128-MFMA block hides the staging latency.
__global__ __launch_bounds__(256, 4) void main_k(
    const unsigned char* __restrict__ Af8s, const unsigned char* __restrict__ Xf8,
    const float* __restrict__ Amut, float* __restrict__ sqws) {
  __shared__ unsigned char A0s[16384];
  __shared__ unsigned char A1s[16384];
  __shared__ float amus[2][D_];
  const int t = threadIdx.x;
  const int w = t >> 6;
  const int L = t & 63;
  const int m = L & 15;
  const int q = L >> 4;
  const int n0 = blockIdx.x * 256;
  const int c0 = blockIdx.y * 8;

  // persistent X B-frags (fp8): lane holds n = n0+w*64+jt*16+m, k = ks*32+q*8 (8 B)
  unsigned long long xf[4][4];
#pragma unroll
  for (int jt = 0; jt < 4; ++jt)
#pragma unroll
    for (int ks = 0; ks < 4; ++ks)
      xf[jt][ks] = *(const unsigned long long*)
          (Xf8 + (size_t)(n0 + w * 64 + jt * 16 + m) * D_ + ks * 32 + q * 8);

  const unsigned char* pl = Af8s + (size_t)c0 * 16384;

  // linear staging: thread t copies 16-B units t+256*it (frag-ordered source)
#define STAGE(SRC, DST)                                                          \
  {                                                                              \
    _Pragma("unroll")                                                            \
    for (int it_ = 0; it_ < 4; ++it_)                                            \
      __builtin_amdgcn_global_load_lds(                                          \
          (const unsigned int*)((SRC) + (it_ * 256 + t) * 16),                   \
          (unsigned int*)((DST) + (it_ * 256 + w * 64) * 16), 16, 0, 0);         \
  }

  STAGE(pl, A0s);
  if (t < 32)
    __builtin_amdgcn_global_load_lds((const unsigned int*)(Amut + (size_t)c0 * D_ + t * 4),
                                     (unsigned int*)&amus[0][0], 16, 0, 0);

  const f4 zero = {0.f, 0.f, 0.f, 0.f};

  auto compute = [&](const unsigned char* buf, const float* amurow, int c) {
    float ss0 = 0.f, ss1 = 0.f, ss2 = 0.f, ss3 = 0.f;
#pragma unroll
    for (int dtl = 0; dtl < 8; ++dtl) {
      ulonglong2 u0 = *(const ulonglong2*)(buf + dtl * 2048 + L * 16);         // ks 0,1
      ulonglong2 u1 = *(const ulonglong2*)(buf + dtl * 2048 + 1024 + L * 16);  // ks 2,3
      f4 amu = *(const f4*)&amurow[dtl * 16 + q * 4];
#pragma unroll
      for (int jt = 0; jt < 4; ++jt) {
        f4 acc = __builtin_amdgcn_mfma_f32_16x16x32_fp8_fp8((long long)u0.x, (long long)xf[jt][0], zero, 0, 0, 0);
        acc = __builtin_amdgcn_mfma_f32_16x16x32_fp8_fp8((long long)u0.y, (long long)xf[jt][1], acc, 0, 0, 0);
        acc = __builtin_amdgcn_mfma_f32_16x16x32_fp8_fp8((long long)u1.x, (long long)xf[jt][2], acc, 0, 0, 0);
        acc = __builtin_amdgcn_mfma_f32_16x16x32_fp8_fp8((long long)u1.y, (long long)xf[jt][3], acc, 0, 0, 0);
        float v0 = acc[0] - amu[0];
        float v1 = acc[1] - amu[1];
        float v2 = acc[2] - amu[2];
        float v3 = acc[3] - amu[3];
        float sj = v0 * v0 + v1 * v1 + v2 * v2 + v3 * v3;
        if (jt == 0) ss0 += sj; else if (jt == 1) ss1 += sj;
        else if (jt == 2) ss2 += sj; else ss3 += sj;
      }
    }
    // fold the 4 quads -> full 128-d sum (replicated over q); quad q owns col-tile
    // jt=q: j = w*64 + q*16 + m = w*64 + L (coalesced 256 B/wave store)
    ss0 += __shfl_xor(ss0, 16, 64);  ss0 += __shfl_xor(ss0, 32, 64);
    ss1 += __shfl_xor(ss1, 16, 64);  ss1 += __shfl_xor(ss1, 32, 64);
    ss2 += __shfl_xor(ss2, 16, 64);  ss2 += __shfl_xor(ss2, 32, 64);
    ss3 += __shfl_xor(ss3, 16, 64);  ss3 += __shfl_xor(ss3, 32, 64);
    float sel = (q == 0) ? ss0 : (q == 1) ? ss1 : (q == 2) ? ss2 : ss3;
    sqws[(size_t)c * N_ + n0 + w * 64 + L] = sel;
  };

  for (int ci2 = 0; ci2 < 4; ++ci2) {
    const int cA = c0 + ci2 * 2;
    __syncthreads();   // drains stage of plane(cA) into A0s
    STAGE(pl + (size_t)(ci2 * 2 + 1) * 16384, A1s);
    if (t < 32)
      __builtin_amdgcn_global_load_lds(
          (const unsigned int*)(Amut + (size_t)(cA + 1) * D_ + t * 4),
          (unsigned int*)&amus[1][0], 16, 0, 0);
    compute(A0s, &amus[0][0], cA);

    __syncthreads();   // drains stage of plane(cA+1) into A1s
    if (ci2 < 3) {
      STAGE(pl + (size_t)(ci2 * 2 + 2) * 16384, A0s);
      if (t < 32)
        __builtin_amdgcn_global_load_lds(
            (const unsigned int*)(Amut + (size_t)(cA + 2) * D_ + t * 4),
            (unsigned int*)&amus[0][0], 16, 0, 0);
    }
    compute(A1s, &amus[1][0], cA + 1);
  }
#undef STAGE
}

// ---------------------------------------------------------------------------
// softmax over c per n; writes Pi to out rows D_..D_+K_-1  (unchanged, known good)
// grid (N/16 = 512), block 256
__global__ __launch_bounds__(256) void softmax_k(const float* __restrict__ sqws,
                                                 const float* __restrict__ gptr,
                                                 float* __restrict__ out) {
  __shared__ float s_ld[K_][17];
  __shared__ float red[16][16];
  __shared__ float red2[16][16];
  const int t = threadIdx.x;
  const int n0 = blockIdx.x * 16;
  const float gamma = *gptr;
  const int nl = t & 15;
  const int cg = t >> 4;
  for (int it = 0; it < 16; ++it) {
    int c = it * 16 + cg;
    s_ld[c][nl] = sqws[(size_t)c * N_ + n0 + nl];
  }
  __syncthreads();
  float mxp = -1e30f;
#pragma unroll
  for (int cc = 0; cc < 16; ++cc)
    mxp = fmaxf(mxp, gamma * s_ld[cg * 16 + cc][nl]);
  red[cg][nl] = mxp;
  __syncthreads();
  float mx = red[0][nl];
#pragma unroll
  for (int g2 = 1; g2 < 16; ++g2) mx = fmaxf(mx, red[g2][nl]);
  float ex[16];
  float z = 0.f;
#pragma unroll
  for (int cc = 0; cc < 16; ++cc) {
    ex[cc] = __expf(gamma * s_ld[cg * 16 + cc][nl] - mx);
    z += ex[cc];
  }
  red2[cg][nl] = z;
  __syncthreads();
  float zz = red2[0][nl];
#pragma unroll
  for (int g2 = 1; g2 < 16; ++g2) zz += red2[g2][nl];
  float rz = 1.f / zz;
#pragma unroll
  for (int cc = 0; cc < 16; ++cc)
    out[(size_t)(D_ + cg * 16 + cc) * N_ + n0 + nl] = ex[cc] * rz;
}

// ---------------------------------------------------------------------------
extern "C" void kernel_launch(void* const* d_in, const int* in_sizes, int n_in,
                              void* d_out, int out_size, void* d_ws, size_t ws_size,
                              hipStream_t stream) {
  const float* X   = (const float*)d_in[0];
  const float* NA  = (const float*)d_in[1];
  const float* Nmu = (const float*)d_in[2];
  const float* g   = (const float*)d_in[3];
  float* out = (float*)d_out;
  char* ws = (char*)d_ws;

  unsigned char* Xf8  = (unsigned char*)(ws);                  // 1 MB
  unsigned char* Af8s = (unsigned char*)(ws + 1048576);        // 4.19 MB
  float* Amut         = (float*)(ws + 5242880);                // 128 KB
  float* sqws         = (float*)(ws + 5373952);                // 8.39 MB

  hipLaunchKernelGGL(prep_x_k, dim3(N_ / 64, D_ / 64), dim3(256), 0, stream, X, out, Xf8);
  hipLaunchKernelGGL(prep_a_k, dim3(8, 16), dim3(256), 0, stream, NA, Af8s);
  hipLaunchKernelGGL(amu_k, dim3(K_), dim3(D_), 0, stream, Af8s, Nmu, Amut);
  hipLaunchKernelGGL(main_k, dim3(N_ / 256, K_ / 8), dim3(256), 0, stream, Af8s, Xf8, Amut, sqws);
  hipLaunchKernelGGL(softmax_k, dim3(N_ / 16), dim3(256), 0, stream, sqws, g, out);
}

// Round 9
// 134.078 us; speedup vs baseline: 2.3663x; 1.0748x over previous
//
#include <hip/hip_runtime.h>

#define D_ 128
#define N_ 8192
#define K_ 256

typedef __attribute__((ext_vector_type(4))) float f4;    // 4 fp32
typedef __attribute__((ext_vector_type(8))) int i8v;     // 8 x i32 (32 B fp8 frag)
typedef __attribute__((ext_vector_type(4))) int i4v;     // 4 x i32 (16 B)

// ---------------------------------------------------------------------------
// prep_x: X (fp32 [D][N]) -> Xf8 (fp8 e4m3 [N][D]) transpose, copy X -> out rows 0..D-1
// grid (N/64, D/64), block 256
__global__ void prep_x_k(const float* __restrict__ X, float* __restrict__ out,
                         unsigned char* __restrict__ Xf8) {
  __shared__ float tile[64][65];
  const int n0 = blockIdx.x * 64;
  const int e0 = blockIdx.y * 64;
  const int t = threadIdx.x;
  const int col = t & 63;
  const int r4 = t >> 6;
  for (int rr = 0; rr < 64; rr += 4) {
    int e = rr + r4;
    float v = X[(size_t)(e0 + e) * N_ + n0 + col];
    tile[e][col] = v;
    out[(size_t)(e0 + e) * N_ + n0 + col] = v;   // exact fp32 copy of X
  }
  __syncthreads();
  const int chunk = t & 15;
  for (int iter = 0; iter < 4; ++iter) {
    int nl = iter * 16 + (t >> 4);
    float v0 = tile[chunk * 4 + 0][nl];
    float v1 = tile[chunk * 4 + 1][nl];
    float v2 = tile[chunk * 4 + 2][nl];
    float v3 = tile[chunk * 4 + 3][nl];
    int pk = __builtin_amdgcn_cvt_pk_fp8_f32(v0, v1, 0, false);
    pk = __builtin_amdgcn_cvt_pk_fp8_f32(v2, v3, pk, true);
    *(int*)&Xf8[(size_t)(n0 + nl) * D_ + e0 + chunk * 4] = pk;
  }
}

// ---------------------------------------------------------------------------
// prep_a: N_A (fp32 [D][D][K]) -> Af8s: fp8, FRAGMENT-ORDERED for the K=128
// scaled MFMA. Per c-plane (16 KB):
//   offset(dtl, h, L=q*16+m) = dtl*2048 + h*1024 + L*16
//   contents: A[d = dtl*16+m][e = q*32 + h*16 + 0..15]
// (lane's full 32-B A-frag = h=0 slab bytes ++ h=1 slab bytes, k = q*32..q*32+31)
// main_k staging is a pure linear copy; LDS reads are conflict-free L*16.
// grid (8 dtl, 16 c-groups), block 256.
__global__ __launch_bounds__(256) void prep_a_k(const float* __restrict__ NA,
                                                unsigned char* __restrict__ Af8s) {
  __shared__ unsigned char AT[16 * 2184];   // [cl][d*136 + e], strides avoid conflicts
  const int dtl = blockIdx.x;
  const int c0 = blockIdx.y * 16;
  const int t = threadIdx.x;
  const int cl = t & 15;
  const int pe = t >> 4;
  // load + convert: 2048 (d,e) pairs, 16 per iter
#pragma unroll 4
  for (int iter = 0; iter < 128; ++iter) {
    int p = iter * 16 + pe;
    int d = p >> 7, e = p & 127;
    float v = NA[((size_t)(dtl * 16 + d) * D_ + e) * K_ + c0 + cl];
    int pk = __builtin_amdgcn_cvt_pk_fp8_f32(v, v, 0, false);
    AT[cl * 2184 + d * 136 + e] = (unsigned char)(pk & 0xff);
  }
  __syncthreads();
  // write phase: 32 units (ucl, h), each one wave x 16 B per lane
  const int w = t >> 6, L = t & 63, q = L >> 4, m = L & 15;
  for (int it = 0; it < 8; ++it) {
    int u = w + it * 4;                 // 0..31
    int ucl = u >> 1, h = u & 1;
    const unsigned char* base = AT + ucl * 2184 + m * 136 + q * 32 + h * 16;
    unsigned long long lo = *(const unsigned long long*)(base);
    unsigned long long hi = *(const unsigned long long*)(base + 8);
    ulonglong2 val; val.x = lo; val.y = hi;
    *(ulonglong2*)(Af8s + (size_t)(c0 + ucl) * 16384 + dtl * 2048 + h * 1024 + L * 16) = val;
  }
}

// ---------------------------------------------------------------------------
// amu: Amut[c][d] = sum_e fp8(A)[d,e,c] * N_mu[e,c]  (same fp8 A as the MFMA).
// grid (K), block (D). Reads the frag-ordered layout:
//   16 B at dtl*2048 + h*1024 + (q*16+m)*16 covers e = q*32 + h*16 + [0..15].
__global__ __launch_bounds__(128) void amu_k(const unsigned char* __restrict__ Af8s,
                                             const float* __restrict__ Nmu,
                                             float* __restrict__ Amut) {
  __shared__ float mu[D_];
  const int c = blockIdx.x;
  const int t = threadIdx.x;   // = d
  mu[t] = Nmu[(size_t)t * K_ + c];
  __syncthreads();
  const int dtl = t >> 4, m = t & 15;
  const unsigned char* base = Af8s + (size_t)c * 16384 + dtl * 2048;
  float s = 0.f;
#pragma unroll
  for (int q = 0; q < 4; ++q)
#pragma unroll
    for (int h = 0; h < 2; ++h) {
      const int4 v = *(const int4*)(base + h * 1024 + (q * 16 + m) * 16);
      const int e0 = q * 32 + h * 16;
      const int wv[4] = {v.x, v.y, v.z, v.w};
#pragma unroll
      for (int wi = 0; wi < 4; ++wi) {
        s += __builtin_amdgcn_cvt_f32_fp8(wv[wi], 0) * mu[e0 + wi * 4 + 0];
        s += __builtin_amdgcn_cvt_f32_fp8(wv[wi], 1) * mu[e0 + wi * 4 + 1];
        s += __builtin_amdgcn_cvt_f32_fp8(wv[wi], 2) * mu[e0 + wi * 4 + 2];
        s += __builtin_amdgcn_cvt_f32_fp8(wv[wi], 3) * mu[e0 + wi * 4 + 3];
      }
    }
  Amut[(size_t)c * D_ + t] = s;
}

// ---------------------------------------------------------------------------
// main (MX-fp8, K=128 per instruction): sq[c][n] = sum_d (sum_e A X - Amu)^2
// grid (N/256, K/8), block 256 (4 waves). Wave w: j in [w*64,+64), ALL 128 d.
// mfma_scale_f32_16x16x128_f8f6f4 with unit scales (E8M0 0x7F = 2^0) runs at
// the MX rate (~2x non-scaled fp8, m148) and does the whole e-reduction in ONE
// instruction -> 32 fully independent MFMAs per wave per c, same C/D layout
// (shape-determined, m121-128) so the epilogue is unchanged from round 8.
// Full-plane (16 KB) double buffer, stage issued right after each barrier.
__global__ __launch_bounds__(256, 4) void main_k(
    const unsigned char* __restrict__ Af8s, const unsigned char* __restrict__ Xf8,
    const float* __restrict__ Amut, float* __restrict__ sqws) {
  __shared__ unsigned char A0s[16384];
  __shared__ unsigned char A1s[16384];
  __shared__ float amus[2][D_];
  const int t = threadIdx.x;
  const int w = t >> 6;
  const int L = t & 63;
  const int m = L & 15;
  const int q = L >> 4;
  const int n0 = blockIdx.x * 256;
  const int c0 = blockIdx.y * 8;

  // persistent X B-frags: lane holds n = n0+w*64+jt*16+m, k = q*32 + [0..31] (32 B)
  i8v xf[4];
#pragma unroll
  for (int jt = 0; jt < 4; ++jt)
    xf[jt] = *(const i8v*)(Xf8 + (size_t)(n0 + w * 64 + jt * 16 + m) * D_ + q * 32);

  const unsigned char* pl = Af8s + (size_t)c0 * 16384;

  // linear staging: thread t copies 16-B units t+256*it (frag-ordered source)
#define STAGE(SRC, DST)                                                          \
  {                                                                              \
    _Pragma("unroll")                                                            \
    for (int it_ = 0; it_ < 4; ++it_)                                            \
      __builtin_amdgcn_global_load_lds(                                          \
          (const unsigned int*)((SRC) + (it_ * 256 + t) * 16),                   \
          (unsigned int*)((DST) + (it_ * 256 + w * 64) * 16), 16, 0, 0);         \
  }

  STAGE(pl, A0s);
  if (t < 32)
    __builtin_amdgcn_global_load_lds((const unsigned int*)(Amut + (size_t)c0 * D_ + t * 4),
                                     (unsigned int*)&amus[0][0], 16, 0, 0);

  const f4 zero = {0.f, 0.f, 0.f, 0.f};

  auto compute = [&](const unsigned char* buf, const float* amurow, int c) {
    float ss0 = 0.f, ss1 = 0.f, ss2 = 0.f, ss3 = 0.f;
#pragma unroll
    for (int dtl = 0; dtl < 8; ++dtl) {
      i4v lo = *(const i4v*)(buf + dtl * 2048 + L * 16);          // k = q*32+0..15
      i4v hi = *(const i4v*)(buf + dtl * 2048 + 1024 + L * 16);   // k = q*32+16..31
      i8v a;
      a[0] = lo[0]; a[1] = lo[1]; a[2] = lo[2]; a[3] = lo[3];
      a[4] = hi[0]; a[5] = hi[1]; a[6] = hi[2]; a[7] = hi[3];
      f4 amu = *(const f4*)&amurow[dtl * 16 + q * 4];
#pragma unroll
      for (int jt = 0; jt < 4; ++jt) {
        f4 acc = __builtin_amdgcn_mfma_scale_f32_16x16x128_f8f6f4(
            a, xf[jt], zero, 0, 0, 0, 0x7f7f7f7f, 0, 0x7f7f7f7f);
        float v0 = acc[0] - amu[0];
        float v1 = acc[1] - amu[1];
        float v2 = acc[2] - amu[2];
        float v3 = acc[3] - amu[3];
        float sj = v0 * v0 + v1 * v1 + v2 * v2 + v3 * v3;
        if (jt == 0) ss0 += sj; else if (jt == 1) ss1 += sj;
        else if (jt == 2) ss2 += sj; else ss3 += sj;
      }
    }
    // fold the 4 quads -> full 128-d sum (replicated over q); quad q owns col-tile
    // jt=q: j = w*64 + q*16 + m = w*64 + L (coalesced 256 B/wave store)
    ss0 += __shfl_xor(ss0, 16, 64);  ss0 += __shfl_xor(ss0, 32, 64);
    ss1 += __shfl_xor(ss1, 16, 64);  ss1 += __shfl_xor(ss1, 32, 64);
    ss2 += __shfl_xor(ss2, 16, 64);  ss2 += __shfl_xor(ss2, 32, 64);
    ss3 += __shfl_xor(ss3, 16, 64);  ss3 += __shfl_xor(ss3, 32, 64);
    float sel = (q == 0) ? ss0 : (q == 1) ? ss1 : (q == 2) ? ss2 : ss3;
    sqws[(size_t)c * N_ + n0 + w * 64 + L] = sel;
  };

  for (int ci2 = 0; ci2 < 4; ++ci2) {
    const int cA = c0 + ci2 * 2;
    __syncthreads();   // drains stage of plane(cA) into A0s
    STAGE(pl + (size_t)(ci2 * 2 + 1) * 16384, A1s);
    if (t < 32)
      __builtin_amdgcn_global_load_lds(
          (const unsigned int*)(Amut + (size_t)(cA + 1) * D_ + t * 4),
          (unsigned int*)&amus[1][0], 16, 0, 0);
    compute(A0s, &amus[0][0], cA);

    __syncthreads();   // drains stage of plane(cA+1) into A1s
    if (ci2 < 3) {
      STAGE(pl + (size_t)(ci2 * 2 + 2) * 16384, A0s);
      if (t < 32)
        __builtin_amdgcn_global_load_lds(
            (const unsigned int*)(Amut + (size_t)(cA + 2) * D_ + t * 4),
            (unsigned int*)&amus[0][0], 16, 0, 0);
    }
    compute(A1s, &amus[1][0], cA + 1);
  }
#undef STAGE
}

// ---------------------------------------------------------------------------
// softmax over c per n; writes Pi to out rows D_..D_+K_-1  (unchanged, known good)
// grid (N/16 = 512), block 256
__global__ __launch_bounds__(256) void softmax_k(const float* __restrict__ sqws,
                                                 const float* __restrict__ gptr,
                                                 float* __restrict__ out) {
  __shared__ float s_ld[K_][17];
  __shared__ float red[16][16];
  __shared__ float red2[16][16];
  const int t = threadIdx.x;
  const int n0 = blockIdx.x * 16;
  const float gamma = *gptr;
  const int nl = t & 15;
  const int cg = t >> 4;
  for (int it = 0; it < 16; ++it) {
    int c = it * 16 + cg;
    s_ld[c][nl] = sqws[(size_t)c * N_ + n0 + nl];
  }
  __syncthreads();
  float mxp = -1e30f;
#pragma unroll
  for (int cc = 0; cc < 16; ++cc)
    mxp = fmaxf(mxp, gamma * s_ld[cg * 16 + cc][nl]);
  red[cg][nl] = mxp;
  __syncthreads();
  float mx = red[0][nl];
#pragma unroll
  for (int g2 = 1; g2 < 16; ++g2) mx = fmaxf(mx, red[g2][nl]);
  float ex[16];
  float z = 0.f;
#pragma unroll
  for (int cc = 0; cc < 16; ++cc) {
    ex[cc] = __expf(gamma * s_ld[cg * 16 + cc][nl] - mx);
    z += ex[cc];
  }
  red2[cg][nl] = z;
  __syncthreads();
  float zz = red2[0][nl];
#pragma unroll
  for (int g2 = 1; g2 < 16; ++g2) zz += red2[g2][nl];
  float rz = 1.f / zz;
#pragma unroll
  for (int cc = 0; cc < 16; ++cc)
    out[(size_t)(D_ + cg * 16 + cc) * N_ + n0 + nl] = ex[cc] * rz;
}

// ---------------------------------------------------------------------------
extern "C" void kernel_launch(void* const* d_in, const int* in_sizes, int n_in,
                              void* d_out, int out_size, void* d_ws, size_t ws_size,
                              hipStream_t stream) {
  const float* X   = (const float*)d_in[0];
  const float* NA  = (const float*)d_in[1];
  const float* Nmu = (const float*)d_in[2];
  const float* g   = (const float*)d_in[3];
  float* out = (float*)d_out;
  char* ws = (char*)d_ws;

  unsigned char* Xf8  = (unsigned char*)(ws);                  // 1 MB
  unsigned char* Af8s = (unsigned char*)(ws + 1048576);        // 4.19 MB
  float* Amut         = (float*)(ws + 5242880);                // 128 KB
  float* sqws         = (float*)(ws + 5373952);                // 8.39 MB

  hipLaunchKernelGGL(prep_x_k, dim3(N_ / 64, D_ / 64), dim3(256), 0, stream, X, out, Xf8);
  hipLaunchKernelGGL(prep_a_k, dim3(8, 16), dim3(256), 0, stream, NA, Af8s);
  hipLaunchKernelGGL(amu_k, dim3(K_), dim3(D_), 0, stream, Af8s, Nmu, Amut);
  hipLaunchKernelGGL(main_k, dim3(N_ / 256, K_ / 8), dim3(256), 0, stream, Af8s, Xf8, Amut, sqws);
  hipLaunchKernelGGL(softmax_k, dim3(N_ / 16), dim3(256), 0, stream, sqws, g, out);
}

// Round 10
// 120.260 us; speedup vs baseline: 2.6382x; 1.1149x over previous
//
#include <hip/hip_runtime.h>

#define D_ 128
#define N_ 8192
#define K_ 256

typedef __attribute__((ext_vector_type(4))) float f4;    // 4 fp32
typedef __attribute__((ext_vector_type(8))) int i8v;     // 8 x i32 (32 B fp8 frag)
typedef __attribute__((ext_vector_type(4))) int i4v;     // 4 x i32 (16 B)

// ---------------------------------------------------------------------------
// prep_x: X (fp32 [D][N]) -> Xf8 (fp8 e4m3 [N][D]) transpose, copy X -> out rows 0..D-1
// grid (N/64, D/64), block 256
__global__ void prep_x_k(const float* __restrict__ X, float* __restrict__ out,
                         unsigned char* __restrict__ Xf8) {
  __shared__ float tile[64][65];
  const int n0 = blockIdx.x * 64;
  const int e0 = blockIdx.y * 64;
  const int t = threadIdx.x;
  const int col = t & 63;
  const int r4 = t >> 6;
  for (int rr = 0; rr < 64; rr += 4) {
    int e = rr + r4;
    float v = X[(size_t)(e0 + e) * N_ + n0 + col];
    tile[e][col] = v;
    out[(size_t)(e0 + e) * N_ + n0 + col] = v;   // exact fp32 copy of X
  }
  __syncthreads();
  const int chunk = t & 15;
  for (int iter = 0; iter < 4; ++iter) {
    int nl = iter * 16 + (t >> 4);
    float v0 = tile[chunk * 4 + 0][nl];
    float v1 = tile[chunk * 4 + 1][nl];
    float v2 = tile[chunk * 4 + 2][nl];
    float v3 = tile[chunk * 4 + 3][nl];
    int pk = __builtin_amdgcn_cvt_pk_fp8_f32(v0, v1, 0, false);
    pk = __builtin_amdgcn_cvt_pk_fp8_f32(v2, v3, pk, true);
    *(int*)&Xf8[(size_t)(n0 + nl) * D_ + e0 + chunk * 4] = pk;
  }
}

// ---------------------------------------------------------------------------
// prep_a: N_A (fp32 [D][D][K]) -> Af8s: fp8, FRAGMENT-ORDERED for the K=128
// scaled MFMA. Per c-plane (16 KB):
//   offset(dtl, h, L=q*16+m) = dtl*2048 + h*1024 + L*16
//   contents: A[d = dtl*16+m][e = q*32 + h*16 + 0..15]
// Load phase vectorized: each thread reads a float4 (4 consecutive c), so each
// (d,e) pair is one fully-coalesced 64-B segment across 4 lanes.
// grid (8 dtl, 16 c-groups), block 256.
__global__ __launch_bounds__(256) void prep_a_k(const float* __restrict__ NA,
                                                unsigned char* __restrict__ Af8s) {
  __shared__ unsigned char AT[16 * 2184];   // [cl][d*136 + e], strides avoid conflicts
  const int dtl = blockIdx.x;
  const int c0 = blockIdx.y * 16;
  const int t = threadIdx.x;
  const int c4 = t & 3;        // which 4-c group
  const int pe = t >> 2;       // 64 (d,e) positions per iter
  // load + convert: 2048 (d,e) pairs, 64 per iter, float4 across c
#pragma unroll 4
  for (int iter = 0; iter < 32; ++iter) {
    int p = iter * 64 + pe;
    int d = p >> 7, e = p & 127;
    float4 v = *(const float4*)&NA[((size_t)(dtl * 16 + d) * D_ + e) * K_ + c0 + c4 * 4];
    int pk0 = __builtin_amdgcn_cvt_pk_fp8_f32(v.x, v.x, 0, false);
    int pk1 = __builtin_amdgcn_cvt_pk_fp8_f32(v.y, v.y, 0, false);
    int pk2 = __builtin_amdgcn_cvt_pk_fp8_f32(v.z, v.z, 0, false);
    int pk3 = __builtin_amdgcn_cvt_pk_fp8_f32(v.w, v.w, 0, false);
    AT[(c4 * 4 + 0) * 2184 + d * 136 + e] = (unsigned char)(pk0 & 0xff);
    AT[(c4 * 4 + 1) * 2184 + d * 136 + e] = (unsigned char)(pk1 & 0xff);
    AT[(c4 * 4 + 2) * 2184 + d * 136 + e] = (unsigned char)(pk2 & 0xff);
    AT[(c4 * 4 + 3) * 2184 + d * 136 + e] = (unsigned char)(pk3 & 0xff);
  }
  __syncthreads();
  // write phase: 32 units (ucl, h), each one wave x 16 B per lane
  const int w = t >> 6, L = t & 63, q = L >> 4, m = L & 15;
  for (int it = 0; it < 8; ++it) {
    int u = w + it * 4;                 // 0..31
    int ucl = u >> 1, h = u & 1;
    const unsigned char* base = AT + ucl * 2184 + m * 136 + q * 32 + h * 16;
    unsigned long long lo = *(const unsigned long long*)(base);
    unsigned long long hi = *(const unsigned long long*)(base + 8);
    ulonglong2 val; val.x = lo; val.y = hi;
    *(ulonglong2*)(Af8s + (size_t)(c0 + ucl) * 16384 + dtl * 2048 + h * 1024 + L * 16) = val;
  }
}

// ---------------------------------------------------------------------------
// amu: Amut[c][d] = -(sum_e fp8(A)[d,e,c] * N_mu[e,c])  -- NEGATED: main_k
// feeds it straight into the MFMA C-operand so acc exits as AX - Amu with
// zero epilogue subtracts. grid (K), block (D). Reads the frag-ordered layout.
__global__ __launch_bounds__(128) void amu_k(const unsigned char* __restrict__ Af8s,
                                             const float* __restrict__ Nmu,
                                             float* __restrict__ Amut) {
  __shared__ float mu[D_];
  const int c = blockIdx.x;
  const int t = threadIdx.x;   // = d
  mu[t] = Nmu[(size_t)t * K_ + c];
  __syncthreads();
  const int dtl = t >> 4, m = t & 15;
  const unsigned char* base = Af8s + (size_t)c * 16384 + dtl * 2048;
  float s = 0.f;
#pragma unroll
  for (int q = 0; q < 4; ++q)
#pragma unroll
    for (int h = 0; h < 2; ++h) {
      const int4 v = *(const int4*)(base + h * 1024 + (q * 16 + m) * 16);
      const int e0 = q * 32 + h * 16;
      const int wv[4] = {v.x, v.y, v.z, v.w};
#pragma unroll
      for (int wi = 0; wi < 4; ++wi) {
        s += __builtin_amdgcn_cvt_f32_fp8(wv[wi], 0) * mu[e0 + wi * 4 + 0];
        s += __builtin_amdgcn_cvt_f32_fp8(wv[wi], 1) * mu[e0 + wi * 4 + 1];
        s += __builtin_amdgcn_cvt_f32_fp8(wv[wi], 2) * mu[e0 + wi * 4 + 2];
        s += __builtin_amdgcn_cvt_f32_fp8(wv[wi], 3) * mu[e0 + wi * 4 + 3];
      }
    }
  Amut[(size_t)c * D_ + t] = -s;
}

// ---------------------------------------------------------------------------
// main (MX-fp8, K=128 per instruction): sq[c][n] = sum_d (sum_e A X - Amu)^2
// grid (N/256, K/8), block 256 (4 waves). Wave w: j in [w*64,+64), ALL 128 d.
// MFMA C-operand = -Amu (pre-negated in Amut) -> epilogue is pure ss += v*v:
// halves epilogue VALU vs round 9 (which did 128 subs + 128 fmas per c-plane).
// Full-plane (16 KB) double buffer, stage issued right after each barrier.
__global__ __launch_bounds__(256, 4) void main_k(
    const unsigned char* __restrict__ Af8s, const unsigned char* __restrict__ Xf8,
    const float* __restrict__ Amut, float* __restrict__ sqws) {
  __shared__ unsigned char A0s[16384];
  __shared__ unsigned char A1s[16384];
  __shared__ float amus[2][D_];
  const int t = threadIdx.x;
  const int w = t >> 6;
  const int L = t & 63;
  const int m = L & 15;
  const int q = L >> 4;
  const int n0 = blockIdx.x * 256;
  const int c0 = blockIdx.y * 8;

  // persistent X B-frags: lane holds n = n0+w*64+jt*16+m, k = q*32 + [0..31] (32 B)
  i8v xf[4];
#pragma unroll
  for (int jt = 0; jt < 4; ++jt)
    xf[jt] = *(const i8v*)(Xf8 + (size_t)(n0 + w * 64 + jt * 16 + m) * D_ + q * 32);

  const unsigned char* pl = Af8s + (size_t)c0 * 16384;

  // linear staging: thread t copies 16-B units t+256*it (frag-ordered source)
#define STAGE(SRC, DST)                                                          \
  {                                                                              \
    _Pragma("unroll")                                                            \
    for (int it_ = 0; it_ < 4; ++it_)                                            \
      __builtin_amdgcn_global_load_lds(                                          \
          (const unsigned int*)((SRC) + (it_ * 256 + t) * 16),                   \
          (unsigned int*)((DST) + (it_ * 256 + w * 64) * 16), 16, 0, 0);         \
  }

  STAGE(pl, A0s);
  if (t < 32)
    __builtin_amdgcn_global_load_lds((const unsigned int*)(Amut + (size_t)c0 * D_ + t * 4),
                                     (unsigned int*)&amus[0][0], 16, 0, 0);

  auto compute = [&](const unsigned char* buf, const float* amurow, int c) {
    float ss0 = 0.f, ss1 = 0.f, ss2 = 0.f, ss3 = 0.f;
#pragma unroll
    for (int dtl = 0; dtl < 8; ++dtl) {
      i4v lo = *(const i4v*)(buf + dtl * 2048 + L * 16);          // k = q*32+0..15
      i4v hi = *(const i4v*)(buf + dtl * 2048 + 1024 + L * 16);   // k = q*32+16..31
      i8v a;
      a[0] = lo[0]; a[1] = lo[1]; a[2] = lo[2]; a[3] = lo[3];
      a[4] = hi[0]; a[5] = hi[1]; a[6] = hi[2]; a[7] = hi[3];
      f4 camu = *(const f4*)&amurow[dtl * 16 + q * 4];   // = -Amu slice
#pragma unroll
      for (int jt = 0; jt < 4; ++jt) {
        f4 acc = __builtin_amdgcn_mfma_scale_f32_16x16x128_f8f6f4(
            a, xf[jt], camu, 0, 0, 0, 0x7f7f7f7f, 0, 0x7f7f7f7f);
        float sj = acc[0] * acc[0] + acc[1] * acc[1] + acc[2] * acc[2] + acc[3] * acc[3];
        if (jt == 0) ss0 += sj; else if (jt == 1) ss1 += sj;
        else if (jt == 2) ss2 += sj; else ss3 += sj;
      }
    }
    // fold the 4 quads -> full 128-d sum (replicated over q); quad q owns col-tile
    // jt=q: j = w*64 + q*16 + m = w*64 + L (coalesced 256 B/wave store)
    ss0 += __shfl_xor(ss0, 16, 64);  ss0 += __shfl_xor(ss0, 32, 64);
    ss1 += __shfl_xor(ss1, 16, 64);  ss1 += __shfl_xor(ss1, 32, 64);
    ss2 += __shfl_xor(ss2, 16, 64);  ss2 += __shfl_xor(ss2, 32, 64);
    ss3 += __shfl_xor(ss3, 16, 64);  ss3 += __shfl_xor(ss3, 32, 64);
    float sel = (q == 0) ? ss0 : (q == 1) ? ss1 : (q == 2) ? ss2 : ss3;
    sqws[(size_t)c * N_ + n0 + w * 64 + L] = sel;
  };

  for (int ci2 = 0; ci2 < 4; ++ci2) {
    const int cA = c0 + ci2 * 2;
    __syncthreads();   // drains stage of plane(cA) into A0s
    STAGE(pl + (size_t)(ci2 * 2 + 1) * 16384, A1s);
    if (t < 32)
      __builtin_amdgcn_global_load_lds(
          (const unsigned int*)(Amut + (size_t)(cA + 1) * D_ + t * 4),
          (unsigned int*)&amus[1][0], 16, 0, 0);
    compute(A0s, &amus[0][0], cA);

    __syncthreads();   // drains stage of plane(cA+1) into A1s
    if (ci2 < 3) {
      STAGE(pl + (size_t)(ci2 * 2 + 2) * 16384, A0s);
      if (t < 32)
        __builtin_amdgcn_global_load_lds(
            (const unsigned int*)(Amut + (size_t)(cA + 2) * D_ + t * 4),
            (unsigned int*)&amus[0][0], 16, 0, 0);
    }
    compute(A1s, &amus[1][0], cA + 1);
  }
#undef STAGE
}

// ---------------------------------------------------------------------------
// softmax over c per n; writes Pi to out rows D_..D_+K_-1  (unchanged, known good)
// grid (N/16 = 512), block 256
__global__ __launch_bounds__(256) void softmax_k(const float* __restrict__ sqws,
                                                 const float* __restrict__ gptr,
                                                 float* __restrict__ out) {
  __shared__ float s_ld[K_][17];
  __shared__ float red[16][16];
  __shared__ float red2[16][16];
  const int t = threadIdx.x;
  const int n0 = blockIdx.x * 16;
  const float gamma = *gptr;
  const int nl = t & 15;
  const int cg = t >> 4;
  for (int it = 0; it < 16; ++it) {
    int c = it * 16 + cg;
    s_ld[c][nl] = sqws[(size_t)c * N_ + n0 + nl];
  }
  __syncthreads();
  float mxp = -1e30f;
#pragma unroll
  for (int cc = 0; cc < 16; ++cc)
    mxp = fmaxf(mxp, gamma * s_ld[cg * 16 + cc][nl]);
  red[cg][nl] = mxp;
  __syncthreads();
  float mx = red[0][nl];
#pragma unroll
  for (int g2 = 1; g2 < 16; ++g2) mx = fmaxf(mx, red[g2][nl]);
  float ex[16];
  float z = 0.f;
#pragma unroll
  for (int cc = 0; cc < 16; ++cc) {
    ex[cc] = __expf(gamma * s_ld[cg * 16 + cc][nl] - mx);
    z += ex[cc];
  }
  red2[cg][nl] = z;
  __syncthreads();
  float zz = red2[0][nl];
#pragma unroll
  for (int g2 = 1; g2 < 16; ++g2) zz += red2[g2][nl];
  float rz = 1.f / zz;
#pragma unroll
  for (int cc = 0; cc < 16; ++cc)
    out[(size_t)(D_ + cg * 16 + cc) * N_ + n0 + nl] = ex[cc] * rz;
}

// ---------------------------------------------------------------------------
extern "C" void kernel_launch(void* const* d_in, const int* in_sizes, int n_in,
                              void* d_out, int out_size, void* d_ws, size_t ws_size,
                              hipStream_t stream) {
  const float* X   = (const float*)d_in[0];
  const float* NA  = (const float*)d_in[1];
  const float* Nmu = (const float*)d_in[2];
  const float* g   = (const float*)d_in[3];
  float* out = (float*)d_out;
  char* ws = (char*)d_ws;

  unsigned char* Xf8  = (unsigned char*)(ws);                  // 1 MB
  unsigned char* Af8s = (unsigned char*)(ws + 1048576);        // 4.19 MB
  float* Amut         = (float*)(ws + 5242880);                // 128 KB
  float* sqws         = (float*)(ws + 5373952);                // 8.39 MB

  hipLaunchKernelGGL(prep_x_k, dim3(N_ / 64, D_ / 64), dim3(256), 0, stream, X, out, Xf8);
  hipLaunchKernelGGL(prep_a_k, dim3(8, 16), dim3(256), 0, stream, NA, Af8s);
  hipLaunchKernelGGL(amu_k, dim3(K_), dim3(D_), 0, stream, Af8s, Nmu, Amut);
  hipLaunchKernelGGL(main_k, dim3(N_ / 256, K_ / 8), dim3(256), 0, stream, Af8s, Xf8, Amut, sqws);
  hipLaunchKernelGGL(softmax_k, dim3(N_ / 16), dim3(256), 0, stream, sqws, g, out);
}

// Round 11
// 117.984 us; speedup vs baseline: 2.6891x; 1.0193x over previous
//
#include <hip/hip_runtime.h>

#define D_ 128
#define N_ 8192
#define K_ 256

typedef __attribute__((ext_vector_type(4))) float f4;    // 4 fp32
typedef __attribute__((ext_vector_type(8))) int i8v;     // 8 x i32 (32 B fp8 frag)
typedef __attribute__((ext_vector_type(4))) int i4v;     // 4 x i32 (16 B)

// ---------------------------------------------------------------------------
// prep_x: X (fp32 [D][N]) -> Xf8 (fp8 e4m3 [N][D]) transpose, copy X -> out rows 0..D-1
// grid (N/64, D/64), block 256
__global__ void prep_x_k(const float* __restrict__ X, float* __restrict__ out,
                         unsigned char* __restrict__ Xf8) {
  __shared__ float tile[64][65];
  const int n0 = blockIdx.x * 64;
  const int e0 = blockIdx.y * 64;
  const int t = threadIdx.x;
  const int col = t & 63;
  const int r4 = t >> 6;
  for (int rr = 0; rr < 64; rr += 4) {
    int e = rr + r4;
    float v = X[(size_t)(e0 + e) * N_ + n0 + col];
    tile[e][col] = v;
    out[(size_t)(e0 + e) * N_ + n0 + col] = v;   // exact fp32 copy of X
  }
  __syncthreads();
  const int chunk = t & 15;
  for (int iter = 0; iter < 4; ++iter) {
    int nl = iter * 16 + (t >> 4);
    float v0 = tile[chunk * 4 + 0][nl];
    float v1 = tile[chunk * 4 + 1][nl];
    float v2 = tile[chunk * 4 + 2][nl];
    float v3 = tile[chunk * 4 + 3][nl];
    int pk = __builtin_amdgcn_cvt_pk_fp8_f32(v0, v1, 0, false);
    pk = __builtin_amdgcn_cvt_pk_fp8_f32(v2, v3, pk, true);
    *(int*)&Xf8[(size_t)(n0 + nl) * D_ + e0 + chunk * 4] = pk;
  }
}

// ---------------------------------------------------------------------------
// prep_a (+ fused amu): N_A (fp32 [D][D][K]) -> Af8s (fp8, frag-ordered, same
// layout as round 10) AND Amut[c][d] = -(sum_e fp8(A)[d,e,c] * N_mu[e,c]).
// The block already holds all 128 e for its 16 d x 16 c in LDS (AT), so the
// amu dot costs ~1 thread-entry each (256 entries = 256 threads) -- this
// replaces the standalone amu_k launch.
// grid (8 dtl, 16 c-groups), block 256.
__global__ __launch_bounds__(256) void prep_a_k(const float* __restrict__ NA,
                                                unsigned char* __restrict__ Af8s,
                                                const float* __restrict__ Nmu,
                                                float* __restrict__ Amut) {
  __shared__ unsigned char AT[16 * 2184];   // [cl][d*136 + e], ~35 KB
  __shared__ float mu_s[16][128];           // [cl][e], 8 KB
  const int dtl = blockIdx.x;
  const int c0 = blockIdx.y * 16;
  const int t = threadIdx.x;
  // load mu: 8 passes, e = pass*16 + (t>>4), cl = t&15 (64-B segments per e-row)
  {
    const int cl = t & 15;
    const int er = t >> 4;
#pragma unroll
    for (int pass = 0; pass < 8; ++pass) {
      int e = pass * 16 + er;
      mu_s[cl][e] = Nmu[(size_t)e * K_ + c0 + cl];
    }
  }
  // load + convert A: float4 across 4 consecutive c per thread
  const int c4 = t & 3;
  const int pe = t >> 2;
#pragma unroll 4
  for (int iter = 0; iter < 32; ++iter) {
    int p = iter * 64 + pe;
    int d = p >> 7, e = p & 127;
    float4 v = *(const float4*)&NA[((size_t)(dtl * 16 + d) * D_ + e) * K_ + c0 + c4 * 4];
    int pk0 = __builtin_amdgcn_cvt_pk_fp8_f32(v.x, v.x, 0, false);
    int pk1 = __builtin_amdgcn_cvt_pk_fp8_f32(v.y, v.y, 0, false);
    int pk2 = __builtin_amdgcn_cvt_pk_fp8_f32(v.z, v.z, 0, false);
    int pk3 = __builtin_amdgcn_cvt_pk_fp8_f32(v.w, v.w, 0, false);
    AT[(c4 * 4 + 0) * 2184 + d * 136 + e] = (unsigned char)(pk0 & 0xff);
    AT[(c4 * 4 + 1) * 2184 + d * 136 + e] = (unsigned char)(pk1 & 0xff);
    AT[(c4 * 4 + 2) * 2184 + d * 136 + e] = (unsigned char)(pk2 & 0xff);
    AT[(c4 * 4 + 3) * 2184 + d * 136 + e] = (unsigned char)(pk3 & 0xff);
  }
  __syncthreads();

  // fused amu: thread t -> (d_loc = t>>4, cl = t&15); dot over all 128 e
  {
    const int d_loc = t >> 4;
    const int cl = t & 15;
    const unsigned char* row = &AT[cl * 2184 + d_loc * 136];
    const float* mr = &mu_s[cl][0];
    float s = 0.f;
#pragma unroll
    for (int j = 0; j < 16; ++j) {               // 16 x int2 (8 e each)
      int2 v = *(const int2*)(row + j * 8);
      const int e0 = j * 8;
      s += __builtin_amdgcn_cvt_f32_fp8(v.x, 0) * mr[e0 + 0];
      s += __builtin_amdgcn_cvt_f32_fp8(v.x, 1) * mr[e0 + 1];
      s += __builtin_amdgcn_cvt_f32_fp8(v.x, 2) * mr[e0 + 2];
      s += __builtin_amdgcn_cvt_f32_fp8(v.x, 3) * mr[e0 + 3];
      s += __builtin_amdgcn_cvt_f32_fp8(v.y, 0) * mr[e0 + 4];
      s += __builtin_amdgcn_cvt_f32_fp8(v.y, 1) * mr[e0 + 5];
      s += __builtin_amdgcn_cvt_f32_fp8(v.y, 2) * mr[e0 + 6];
      s += __builtin_amdgcn_cvt_f32_fp8(v.y, 3) * mr[e0 + 7];
    }
    Amut[(size_t)(c0 + cl) * D_ + dtl * 16 + d_loc] = -s;   // negated for MFMA C-op
  }

  // write phase: 32 units (ucl, h), each one wave x 16 B per lane
  const int w = t >> 6, L = t & 63, q = L >> 4, m = L & 15;
  for (int it = 0; it < 8; ++it) {
    int u = w + it * 4;                 // 0..31
    int ucl = u >> 1, h = u & 1;
    const unsigned char* base = AT + ucl * 2184 + m * 136 + q * 32 + h * 16;
    unsigned long long lo = *(const unsigned long long*)(base);
    unsigned long long hi = *(const unsigned long long*)(base + 8);
    ulonglong2 val; val.x = lo; val.y = hi;
    *(ulonglong2*)(Af8s + (size_t)(c0 + ucl) * 16384 + dtl * 2048 + h * 1024 + L * 16) = val;
  }
}

// ---------------------------------------------------------------------------
// main (MX-fp8, K=128 per instruction): sq[c][n] = sum_d (sum_e A X - Amu)^2
// grid (N/256, K/8), block 256 (4 waves). Wave w: j in [w*64,+64), ALL 128 d.
// MFMA C-operand = -Amu (pre-negated) -> epilogue is pure ss += v*v.
// Full-plane (16 KB) double buffer, stage issued right after each barrier.
// UNCHANGED from round 10 (verified ~80% of the 14.7 us MX floor).
__global__ __launch_bounds__(256, 4) void main_k(
    const unsigned char* __restrict__ Af8s, const unsigned char* __restrict__ Xf8,
    const float* __restrict__ Amut, float* __restrict__ sqws) {
  __shared__ unsigned char A0s[16384];
  __shared__ unsigned char A1s[16384];
  __shared__ float amus[2][D_];
  const int t = threadIdx.x;
  const int w = t >> 6;
  const int L = t & 63;
  const int m = L & 15;
  const int q = L >> 4;
  const int n0 = blockIdx.x * 256;
  const int c0 = blockIdx.y * 8;

  // persistent X B-frags: lane holds n = n0+w*64+jt*16+m, k = q*32 + [0..31] (32 B)
  i8v xf[4];
#pragma unroll
  for (int jt = 0; jt < 4; ++jt)
    xf[jt] = *(const i8v*)(Xf8 + (size_t)(n0 + w * 64 + jt * 16 + m) * D_ + q * 32);

  const unsigned char* pl = Af8s + (size_t)c0 * 16384;

#define STAGE(SRC, DST)                                                          \
  {                                                                              \
    _Pragma("unroll")                                                            \
    for (int it_ = 0; it_ < 4; ++it_)                                            \
      __builtin_amdgcn_global_load_lds(                                          \
          (const unsigned int*)((SRC) + (it_ * 256 + t) * 16),                   \
          (unsigned int*)((DST) + (it_ * 256 + w * 64) * 16), 16, 0, 0);         \
  }

  STAGE(pl, A0s);
  if (t < 32)
    __builtin_amdgcn_global_load_lds((const unsigned int*)(Amut + (size_t)c0 * D_ + t * 4),
                                     (unsigned int*)&amus[0][0], 16, 0, 0);

  auto compute = [&](const unsigned char* buf, const float* amurow, int c) {
    float ss0 = 0.f, ss1 = 0.f, ss2 = 0.f, ss3 = 0.f;
#pragma unroll
    for (int dtl = 0; dtl < 8; ++dtl) {
      i4v lo = *(const i4v*)(buf + dtl * 2048 + L * 16);          // k = q*32+0..15
      i4v hi = *(const i4v*)(buf + dtl * 2048 + 1024 + L * 16);   // k = q*32+16..31
      i8v a;
      a[0] = lo[0]; a[1] = lo[1]; a[2] = lo[2]; a[3] = lo[3];
      a[4] = hi[0]; a[5] = hi[1]; a[6] = hi[2]; a[7] = hi[3];
      f4 camu = *(const f4*)&amurow[dtl * 16 + q * 4];   // = -Amu slice
#pragma unroll
      for (int jt = 0; jt < 4; ++jt) {
        f4 acc = __builtin_amdgcn_mfma_scale_f32_16x16x128_f8f6f4(
            a, xf[jt], camu, 0, 0, 0, 0x7f7f7f7f, 0, 0x7f7f7f7f);
        float sj = acc[0] * acc[0] + acc[1] * acc[1] + acc[2] * acc[2] + acc[3] * acc[3];
        if (jt == 0) ss0 += sj; else if (jt == 1) ss1 += sj;
        else if (jt == 2) ss2 += sj; else ss3 += sj;
      }
    }
    ss0 += __shfl_xor(ss0, 16, 64);  ss0 += __shfl_xor(ss0, 32, 64);
    ss1 += __shfl_xor(ss1, 16, 64);  ss1 += __shfl_xor(ss1, 32, 64);
    ss2 += __shfl_xor(ss2, 16, 64);  ss2 += __shfl_xor(ss2, 32, 64);
    ss3 += __shfl_xor(ss3, 16, 64);  ss3 += __shfl_xor(ss3, 32, 64);
    float sel = (q == 0) ? ss0 : (q == 1) ? ss1 : (q == 2) ? ss2 : ss3;
    sqws[(size_t)c * N_ + n0 + w * 64 + L] = sel;
  };

  for (int ci2 = 0; ci2 < 4; ++ci2) {
    const int cA = c0 + ci2 * 2;
    __syncthreads();   // drains stage of plane(cA) into A0s
    STAGE(pl + (size_t)(ci2 * 2 + 1) * 16384, A1s);
    if (t < 32)
      __builtin_amdgcn_global_load_lds(
          (const unsigned int*)(Amut + (size_t)(cA + 1) * D_ + t * 4),
          (unsigned int*)&amus[1][0], 16, 0, 0);
    compute(A0s, &amus[0][0], cA);

    __syncthreads();   // drains stage of plane(cA+1) into A1s
    if (ci2 < 3) {
      STAGE(pl + (size_t)(ci2 * 2 + 2) * 16384, A0s);
      if (t < 32)
        __builtin_amdgcn_global_load_lds(
            (const unsigned int*)(Amut + (size_t)(cA + 2) * D_ + t * 4),
            (unsigned int*)&amus[0][0], 16, 0, 0);
    }
    compute(A1s, &amus[1][0], cA + 1);
  }
#undef STAGE
}

// ---------------------------------------------------------------------------
// softmax v2: 32-n tiles (256 blocks), float4 loads (128-B segments per c-row),
// exp values in registers. grid (N/32), block 256: nl = t&31, cg = t>>5 (8 x 32 c).
__global__ __launch_bounds__(256) void softmax_k(const float* __restrict__ sqws,
                                                 const float* __restrict__ gptr,
                                                 float* __restrict__ out) {
  __shared__ float s_ld[256][36];   // pad 36: f4-aligned rows, conflict-free reads
  __shared__ float red[8][32];
  __shared__ float red2[8][32];
  const int t = threadIdx.x;
  const int n0 = blockIdx.x * 32;
  const float gamma = *gptr;
  // load: 8 float4 per thread; f = it*256 + t -> c = f>>3, nq = f&7
#pragma unroll
  for (int it = 0; it < 8; ++it) {
    int f = it * 256 + t;
    int c = f >> 3, nq = f & 7;
    *(float4*)&s_ld[c][nq * 4] = *(const float4*)&sqws[(size_t)c * N_ + n0 + nq * 4];
  }
  __syncthreads();
  const int nl = t & 31;
  const int cg = t >> 5;
  float mxp = -1e30f;
#pragma unroll
  for (int cc = 0; cc < 32; ++cc)
    mxp = fmaxf(mxp, gamma * s_ld[cg * 32 + cc][nl]);
  red[cg][nl] = mxp;
  __syncthreads();
  float mx = red[0][nl];
#pragma unroll
  for (int g2 = 1; g2 < 8; ++g2) mx = fmaxf(mx, red[g2][nl]);
  float ex[32];
  float z = 0.f;
#pragma unroll
  for (int cc = 0; cc < 32; ++cc) {
    ex[cc] = __expf(gamma * s_ld[cg * 32 + cc][nl] - mx);
    z += ex[cc];
  }
  red2[cg][nl] = z;
  __syncthreads();
  float zz = red2[0][nl];
#pragma unroll
  for (int g2 = 1; g2 < 8; ++g2) zz += red2[g2][nl];
  float rz = 1.f / zz;
#pragma unroll
  for (int cc = 0; cc < 32; ++cc)
    out[(size_t)(D_ + cg * 32 + cc) * N_ + n0 + nl] = ex[cc] * rz;
}

// ---------------------------------------------------------------------------
extern "C" void kernel_launch(void* const* d_in, const int* in_sizes, int n_in,
                              void* d_out, int out_size, void* d_ws, size_t ws_size,
                              hipStream_t stream) {
  const float* X   = (const float*)d_in[0];
  const float* NA  = (const float*)d_in[1];
  const float* Nmu = (const float*)d_in[2];
  const float* g   = (const float*)d_in[3];
  float* out = (float*)d_out;
  char* ws = (char*)d_ws;

  unsigned char* Xf8  = (unsigned char*)(ws);                  // 1 MB
  unsigned char* Af8s = (unsigned char*)(ws + 1048576);        // 4.19 MB
  float* Amut         = (float*)(ws + 5242880);                // 128 KB
  float* sqws         = (float*)(ws + 5373952);                // 8.39 MB

  hipLaunchKernelGGL(prep_x_k, dim3(N_ / 64, D_ / 64), dim3(256), 0, stream, X, out, Xf8);
  hipLaunchKernelGGL(prep_a_k, dim3(8, 16), dim3(256), 0, stream, NA, Af8s, Nmu, Amut);
  hipLaunchKernelGGL(main_k, dim3(N_ / 256, K_ / 8), dim3(256), 0, stream, Af8s, Xf8, Amut, sqws);
  hipLaunchKernelGGL(softmax_k, dim3(N_ / 32), dim3(256), 0, stream, sqws, g, out);
}

// Round 12
// 112.495 us; speedup vs baseline: 2.8203x; 1.0488x over previous
//
#include <hip/hip_runtime.h>

#define D_ 128
#define N_ 8192
#define K_ 256

typedef __attribute__((ext_vector_type(4))) float f4;    // 4 fp32
typedef __attribute__((ext_vector_type(8))) int i8v;     // 8 x i32 (32 B fp8 frag)
typedef __attribute__((ext_vector_type(4))) int i4v;     // 4 x i32 (16 B)

// ---------------------------------------------------------------------------
// prep_k: fused prep_x + prep_a(+amu). Flat grid of 512 blocks:
//   blocks 0..255   : X (fp32 [D][N]) -> Xf8 (fp8 [N][D]) transpose + exact
//                     fp32 copy of X into out rows 0..D-1. (was prep_x_k)
//   blocks 256..511 : N_A (fp32 [D][D][K]) -> Af8s (fp8, frag-ordered; same
//                     global layout as rounds 9-11) + fused negated amu.
//                     c-group split 16 -> 8 doubles parallelism vs round 11
//                     (was 128 blocks = 0.5 block/CU, half the GPU idle).
// Both roles fit one 21.6 KB LDS union; one launch instead of two.
__global__ __launch_bounds__(256) void prep_k(
    const float* __restrict__ X, float* __restrict__ out,
    unsigned char* __restrict__ Xf8, const float* __restrict__ NA,
    unsigned char* __restrict__ Af8s, const float* __restrict__ Nmu,
    float* __restrict__ Amut) {
  __shared__ __align__(16) char smem[21568];
  const int t = threadIdx.x;
  const int id = blockIdx.x;

  if (id < 256) {
    // ---------------- prep_x role ----------------
    float (*tile)[65] = (float (*)[65])smem;   // 64 x 65 floats = 16.6 KB
    const int n0 = (id & 127) * 64;
    const int e0 = (id >> 7) * 64;
    const int col = t & 63;
    const int r4 = t >> 6;
    for (int rr = 0; rr < 64; rr += 4) {
      int e = rr + r4;
      float v = X[(size_t)(e0 + e) * N_ + n0 + col];
      tile[e][col] = v;
      out[(size_t)(e0 + e) * N_ + n0 + col] = v;   // exact fp32 copy of X
    }
    __syncthreads();
    const int chunk = t & 15;
    for (int iter = 0; iter < 4; ++iter) {
      int nl = iter * 16 + (t >> 4);
      float v0 = tile[chunk * 4 + 0][nl];
      float v1 = tile[chunk * 4 + 1][nl];
      float v2 = tile[chunk * 4 + 2][nl];
      float v3 = tile[chunk * 4 + 3][nl];
      int pk = __builtin_amdgcn_cvt_pk_fp8_f32(v0, v1, 0, false);
      pk = __builtin_amdgcn_cvt_pk_fp8_f32(v2, v3, pk, true);
      *(int*)&Xf8[(size_t)(n0 + nl) * D_ + e0 + chunk * 4] = pk;
    }
  } else {
    // ---------------- prep_a (+amu) role ----------------
    const int aid = id - 256;
    const int dtl = aid & 7;           // d-tile of 16
    const int c0 = (aid >> 3) * 8;     // 8 c per block (32 groups)
    unsigned char* AT = (unsigned char*)smem;        // [cl][d*136+e], 8*2184=17472 B
    float* mu_s = (float*)(smem + 17472);            // [cl][e], 8*128*4 = 4096 B
    // load mu: cl = t&7, er = t>>3; 4 passes of 32 e
    {
      const int cl = t & 7;
      const int er = t >> 3;
#pragma unroll
      for (int pass = 0; pass < 4; ++pass) {
        int e = pass * 32 + er;
        mu_s[cl * 128 + e] = Nmu[(size_t)e * K_ + c0 + cl];
      }
    }
    // load + convert A: float4 across 4 consecutive c; c4 = t&1, pe = t>>1
    const int c4 = t & 1;
    const int pe = t >> 1;
#pragma unroll 4
    for (int iter = 0; iter < 16; ++iter) {
      int p = iter * 128 + pe;
      int d = p >> 7, e = p & 127;
      float4 v = *(const float4*)&NA[((size_t)(dtl * 16 + d) * D_ + e) * K_ + c0 + c4 * 4];
      int pk0 = __builtin_amdgcn_cvt_pk_fp8_f32(v.x, v.x, 0, false);
      int pk1 = __builtin_amdgcn_cvt_pk_fp8_f32(v.y, v.y, 0, false);
      int pk2 = __builtin_amdgcn_cvt_pk_fp8_f32(v.z, v.z, 0, false);
      int pk3 = __builtin_amdgcn_cvt_pk_fp8_f32(v.w, v.w, 0, false);
      AT[(c4 * 4 + 0) * 2184 + d * 136 + e] = (unsigned char)(pk0 & 0xff);
      AT[(c4 * 4 + 1) * 2184 + d * 136 + e] = (unsigned char)(pk1 & 0xff);
      AT[(c4 * 4 + 2) * 2184 + d * 136 + e] = (unsigned char)(pk2 & 0xff);
      AT[(c4 * 4 + 3) * 2184 + d * 136 + e] = (unsigned char)(pk3 & 0xff);
    }
    __syncthreads();
    // fused amu: 128 entries (16 d x 8 c); negated for the MFMA C-operand
    if (t < 128) {
      const int d_loc = t >> 3;
      const int cl = t & 7;
      const unsigned char* row = &AT[cl * 2184 + d_loc * 136];
      const float* mr = &mu_s[cl * 128];
      float s = 0.f;
#pragma unroll
      for (int j = 0; j < 16; ++j) {             // 16 x int2 (8 e each)
        int2 v = *(const int2*)(row + j * 8);
        const int e0 = j * 8;
        s += __builtin_amdgcn_cvt_f32_fp8(v.x, 0) * mr[e0 + 0];
        s += __builtin_amdgcn_cvt_f32_fp8(v.x, 1) * mr[e0 + 1];
        s += __builtin_amdgcn_cvt_f32_fp8(v.x, 2) * mr[e0 + 2];
        s += __builtin_amdgcn_cvt_f32_fp8(v.x, 3) * mr[e0 + 3];
        s += __builtin_amdgcn_cvt_f32_fp8(v.y, 0) * mr[e0 + 4];
        s += __builtin_amdgcn_cvt_f32_fp8(v.y, 1) * mr[e0 + 5];
        s += __builtin_amdgcn_cvt_f32_fp8(v.y, 2) * mr[e0 + 6];
        s += __builtin_amdgcn_cvt_f32_fp8(v.y, 3) * mr[e0 + 7];
      }
      Amut[(size_t)(c0 + cl) * D_ + dtl * 16 + d_loc] = -s;
    }
    // write phase: 16 units (ucl 0..7, h 0..1), each one wave x 16 B per lane
    const int w = t >> 6, L = t & 63, q = L >> 4, m = L & 15;
#pragma unroll
    for (int it = 0; it < 4; ++it) {
      int u = w + it * 4;                 // 0..15
      int ucl = u >> 1, h = u & 1;
      const unsigned char* base = AT + ucl * 2184 + m * 136 + q * 32 + h * 16;
      unsigned long long lo = *(const unsigned long long*)(base);
      unsigned long long hi = *(const unsigned long long*)(base + 8);
      ulonglong2 val; val.x = lo; val.y = hi;
      *(ulonglong2*)(Af8s + (size_t)(c0 + ucl) * 16384 + dtl * 2048 + h * 1024 + L * 16) = val;
    }
  }
}

// ---------------------------------------------------------------------------
// main (MX-fp8, K=128 per instruction): sq[c][n] = sum_d (sum_e A X - Amu)^2
// grid (N/256, K/8), block 256 (4 waves). Wave w: j in [w*64,+64), ALL 128 d.
// MFMA C-operand = -Amu (pre-negated) -> epilogue is pure ss += v*v.
// Full-plane (16 KB) double buffer, stage issued right after each barrier.
// UNCHANGED from rounds 10-11 (verified ~80% of the 14.7 us MX floor).
__global__ __launch_bounds__(256, 4) void main_k(
    const unsigned char* __restrict__ Af8s, const unsigned char* __restrict__ Xf8,
    const float* __restrict__ Amut, float* __restrict__ sqws) {
  __shared__ unsigned char A0s[16384];
  __shared__ unsigned char A1s[16384];
  __shared__ float amus[2][D_];
  const int t = threadIdx.x;
  const int w = t >> 6;
  const int L = t & 63;
  const int m = L & 15;
  const int q = L >> 4;
  const int n0 = blockIdx.x * 256;
  const int c0 = blockIdx.y * 8;

  // persistent X B-frags: lane holds n = n0+w*64+jt*16+m, k = q*32 + [0..31] (32 B)
  i8v xf[4];
#pragma unroll
  for (int jt = 0; jt < 4; ++jt)
    xf[jt] = *(const i8v*)(Xf8 + (size_t)(n0 + w * 64 + jt * 16 + m) * D_ + q * 32);

  const unsigned char* pl = Af8s + (size_t)c0 * 16384;

#define STAGE(SRC, DST)                                                          \
  {                                                                              \
    _Pragma("unroll")                                                            \
    for (int it_ = 0; it_ < 4; ++it_)                                            \
      __builtin_amdgcn_global_load_lds(                                          \
          (const unsigned int*)((SRC) + (it_ * 256 + t) * 16),                   \
          (unsigned int*)((DST) + (it_ * 256 + w * 64) * 16), 16, 0, 0);         \
  }

  STAGE(pl, A0s);
  if (t < 32)
    __builtin_amdgcn_global_load_lds((const unsigned int*)(Amut + (size_t)c0 * D_ + t * 4),
                                     (unsigned int*)&amus[0][0], 16, 0, 0);

  auto compute = [&](const unsigned char* buf, const float* amurow, int c) {
    float ss0 = 0.f, ss1 = 0.f, ss2 = 0.f, ss3 = 0.f;
#pragma unroll
    for (int dtl = 0; dtl < 8; ++dtl) {
      i4v lo = *(const i4v*)(buf + dtl * 2048 + L * 16);          // k = q*32+0..15
      i4v hi = *(const i4v*)(buf + dtl * 2048 + 1024 + L * 16);   // k = q*32+16..31
      i8v a;
      a[0] = lo[0]; a[1] = lo[1]; a[2] = lo[2]; a[3] = lo[3];
      a[4] = hi[0]; a[5] = hi[1]; a[6] = hi[2]; a[7] = hi[3];
      f4 camu = *(const f4*)&amurow[dtl * 16 + q * 4];   // = -Amu slice
#pragma unroll
      for (int jt = 0; jt < 4; ++jt) {
        f4 acc = __builtin_amdgcn_mfma_scale_f32_16x16x128_f8f6f4(
            a, xf[jt], camu, 0, 0, 0, 0x7f7f7f7f, 0, 0x7f7f7f7f);
        float sj = acc[0] * acc[0] + acc[1] * acc[1] + acc[2] * acc[2] + acc[3] * acc[3];
        if (jt == 0) ss0 += sj; else if (jt == 1) ss1 += sj;
        else if (jt == 2) ss2 += sj; else ss3 += sj;
      }
    }
    ss0 += __shfl_xor(ss0, 16, 64);  ss0 += __shfl_xor(ss0, 32, 64);
    ss1 += __shfl_xor(ss1, 16, 64);  ss1 += __shfl_xor(ss1, 32, 64);
    ss2 += __shfl_xor(ss2, 16, 64);  ss2 += __shfl_xor(ss2, 32, 64);
    ss3 += __shfl_xor(ss3, 16, 64);  ss3 += __shfl_xor(ss3, 32, 64);
    float sel = (q == 0) ? ss0 : (q == 1) ? ss1 : (q == 2) ? ss2 : ss3;
    sqws[(size_t)c * N_ + n0 + w * 64 + L] = sel;
  };

  for (int ci2 = 0; ci2 < 4; ++ci2) {
    const int cA = c0 + ci2 * 2;
    __syncthreads();   // drains stage of plane(cA) into A0s
    STAGE(pl + (size_t)(ci2 * 2 + 1) * 16384, A1s);
    if (t < 32)
      __builtin_amdgcn_global_load_lds(
          (const unsigned int*)(Amut + (size_t)(cA + 1) * D_ + t * 4),
          (unsigned int*)&amus[1][0], 16, 0, 0);
    compute(A0s, &amus[0][0], cA);

    __syncthreads();   // drains stage of plane(cA+1) into A1s
    if (ci2 < 3) {
      STAGE(pl + (size_t)(ci2 * 2 + 2) * 16384, A0s);
      if (t < 32)
        __builtin_amdgcn_global_load_lds(
            (const unsigned int*)(Amut + (size_t)(cA + 2) * D_ + t * 4),
            (unsigned int*)&amus[0][0], 16, 0, 0);
    }
    compute(A1s, &amus[1][0], cA + 1);
  }
#undef STAGE
}

// ---------------------------------------------------------------------------
// softmax v2: 32-n tiles (256 blocks), float4 loads (128-B segments per c-row),
// exp values in registers. grid (N/32), block 256: nl = t&31, cg = t>>5 (8 x 32 c).
// UNCHANGED from round 11.
__global__ __launch_bounds__(256) void softmax_k(const float* __restrict__ sqws,
                                                 const float* __restrict__ gptr,
                                                 float* __restrict__ out) {
  __shared__ float s_ld[256][36];   // pad 36: f4-aligned rows, conflict-free reads
  __shared__ float red[8][32];
  __shared__ float red2[8][32];
  const int t = threadIdx.x;
  const int n0 = blockIdx.x * 32;
  const float gamma = *gptr;
#pragma unroll
  for (int it = 0; it < 8; ++it) {
    int f = it * 256 + t;
    int c = f >> 3, nq = f & 7;
    *(float4*)&s_ld[c][nq * 4] = *(const float4*)&sqws[(size_t)c * N_ + n0 + nq * 4];
  }
  __syncthreads();
  const int nl = t & 31;
  const int cg = t >> 5;
  float mxp = -1e30f;
#pragma unroll
  for (int cc = 0; cc < 32; ++cc)
    mxp = fmaxf(mxp, gamma * s_ld[cg * 32 + cc][nl]);
  red[cg][nl] = mxp;
  __syncthreads();
  float mx = red[0][nl];
#pragma unroll
  for (int g2 = 1; g2 < 8; ++g2) mx = fmaxf(mx, red[g2][nl]);
  float ex[32];
  float z = 0.f;
#pragma unroll
  for (int cc = 0; cc < 32; ++cc) {
    ex[cc] = __expf(gamma * s_ld[cg * 32 + cc][nl] - mx);
    z += ex[cc];
  }
  red2[cg][nl] = z;
  __syncthreads();
  float zz = red2[0][nl];
#pragma unroll
  for (int g2 = 1; g2 < 8; ++g2) zz += red2[g2][nl];
  float rz = 1.f / zz;
#pragma unroll
  for (int cc = 0; cc < 32; ++cc)
    out[(size_t)(D_ + cg * 32 + cc) * N_ + n0 + nl] = ex[cc] * rz;
}

// ---------------------------------------------------------------------------
extern "C" void kernel_launch(void* const* d_in, const int* in_sizes, int n_in,
                              void* d_out, int out_size, void* d_ws, size_t ws_size,
                              hipStream_t stream) {
  const float* X   = (const float*)d_in[0];
  const float* NA  = (const float*)d_in[1];
  const float* Nmu = (const float*)d_in[2];
  const float* g   = (const float*)d_in[3];
  float* out = (float*)d_out;
  char* ws = (char*)d_ws;

  unsigned char* Xf8  = (unsigned char*)(ws);                  // 1 MB
  unsigned char* Af8s = (unsigned char*)(ws + 1048576);        // 4.19 MB
  float* Amut         = (float*)(ws + 5242880);                // 128 KB
  float* sqws         = (float*)(ws + 5373952);                // 8.39 MB

  hipLaunchKernelGGL(prep_k, dim3(512), dim3(256), 0, stream,
                     X, out, Xf8, NA, Af8s, Nmu, Amut);
  hipLaunchKernelGGL(main_k, dim3(N_ / 256, K_ / 8), dim3(256), 0, stream,
                     Af8s, Xf8, Amut, sqws);
  hipLaunchKernelGGL(softmax_k, dim3(N_ / 32), dim3(256), 0, stream, sqws, g, out);
}